// Round 10
// baseline (172.198 us; speedup 1.0000x reference)
//
#include <hip/hip_runtime.h>
#include <math.h>

#define BB 8
#define NN 512
#define FF 128
#define TT 32
#define DD 64
constexpr float EPS = 1e-6f;

typedef _Float16 half8 __attribute__((ext_vector_type(8)));
typedef _Float16 half4v __attribute__((ext_vector_type(4)));
typedef float f32x4 __attribute__((ext_vector_type(4)));

extern __shared__ char dynsmem[];

__device__ __forceinline__ float fast_tanh(float v) {
    float e = __expf(2.f * v);
    return 1.f - 2.f * __builtin_amdgcn_rcpf(e + 1.f);
}

__device__ __forceinline__ void gl_lds16(const void* g, void* l) {
    __builtin_amdgcn_global_load_lds((const __attribute__((address_space(1))) unsigned int*)g,
                                     (__attribute__((address_space(3))) unsigned int*)l,
                                     16, 0, 0);
}

// ---------------- Stage 0: transpose W[64][128] -> wT[f][d] (32KB, L1-resident for z) ----------------
__global__ __launch_bounds__(256) void wtrans_kernel(const float* __restrict__ W,
                                                     float* __restrict__ wT) {
    const int tid = threadIdx.x;
    const float4* W4 = (const float4*)W;
    #pragma unroll
    for (int it = 0; it < 8; ++it) {
        int idx4 = tid + it * 256;
        float4 w = W4[idx4];
        int d = idx4 >> 5;
        int f = (idx4 & 31) * 4;
        wT[(f + 0) * 64 + d] = w.x;
        wT[(f + 1) * 64 + d] = w.y;
        wT[(f + 2) * 64 + d] = w.z;
        wT[(f + 3) * 64 + d] = w.w;
    }
}

// ---------------- Stage 1: z = tanh(x @ W^T + b) -> fp16 hi/lo split, swizzled d-major ----------------
// z layout: [b][t][n][octet ^ (n&7)][8]
// W read from global wT (L1-hot 32KB shared by all co-resident blocks) -> LDS holds ONLY xs
// (33792 B) -> 4 blocks/CU, 16 waves/CU (was 2 blocks / 8 waves with W in LDS).
// grid: B * (N/2) = 2048 blocks, 256 threads
__global__ __launch_bounds__(256, 4) void z6_kernel(const float* __restrict__ x,
                                                    const float* __restrict__ wT,
                                                    const float* __restrict__ bias,
                                                    _Float16* __restrict__ zh,
                                                    _Float16* __restrict__ zl,
                                                    float* __restrict__ sqv,
                                                    float* __restrict__ nvv) {
    float* xs = (float*)dynsmem;          // 2*32*132 floats
    const int tid = threadIdx.x;
    const int b  = blockIdx.x >> 8;
    const int n0 = (blockIdx.x & 255) * 2;

    // x[b][n0..n0+1][F][T] (8192 floats) -> xs[ns][t][f] (padded stride 132)
    const float4* x4 = (const float4*)(x + ((size_t)b * NN + n0) * FF * TT);
    #pragma unroll
    for (int it = 0; it < 8; ++it) {
        int idx4 = tid + it * 256;
        float4 v = x4[idx4];
        int e   = idx4 * 4;
        int ns  = e >> 12;
        int rem = e & 4095;
        int f   = rem >> 5;
        int t   = rem & 31;
        float* base = xs + ns * (32 * 132) + t * 132 + f;
        base[0 * 132] = v.x;
        base[1 * 132] = v.y;
        base[2 * 132] = v.z;
        base[3 * 132] = v.w;
    }
    __syncthreads();

    const int t  = tid >> 3;
    const int dg = tid & 7;
    const int d0 = dg * 8;
    float acc[2][8];
    #pragma unroll
    for (int ns = 0; ns < 2; ++ns)
        #pragma unroll
        for (int dd = 0; dd < 8; ++dd) acc[ns][dd] = 0.f;

    #pragma unroll 4
    for (int fc = 0; fc < FF; fc += 4) {
        float wv[4][8];
        #pragma unroll
        for (int k = 0; k < 4; ++k) {
            float4 a = *(const float4*)&wT[(fc + k) * 64 + d0];
            float4 c = *(const float4*)&wT[(fc + k) * 64 + d0 + 4];
            wv[k][0] = a.x; wv[k][1] = a.y; wv[k][2] = a.z; wv[k][3] = a.w;
            wv[k][4] = c.x; wv[k][5] = c.y; wv[k][6] = c.z; wv[k][7] = c.w;
        }
        #pragma unroll
        for (int ns = 0; ns < 2; ++ns) {
            float4 xv = *(const float4*)&xs[ns * (32 * 132) + t * 132 + fc];
            float xk[4] = {xv.x, xv.y, xv.z, xv.w};
            #pragma unroll
            for (int dd = 0; dd < 8; ++dd) {
                acc[ns][dd] += xk[0] * wv[0][dd] + xk[1] * wv[1][dd]
                             + xk[2] * wv[2][dd] + xk[3] * wv[3][dd];
            }
        }
    }

    float bb[8];
    #pragma unroll
    for (int dd = 0; dd < 8; ++dd) bb[dd] = bias[d0 + dd];

    const size_t rowbase = ((size_t)b * TT + t) * NN + n0;
    float sqp[2];
    #pragma unroll
    for (int ns = 0; ns < 2; ++ns) {
        half8 hv, lv;
        float sp = 0.f;
        #pragma unroll
        for (int dd = 0; dd < 8; ++dd) {
            float zf = fast_tanh(acc[ns][dd] + bb[dd]);
            sp += zf * zf;
            _Float16 h = (_Float16)zf;
            hv[dd] = h;
            lv[dd] = (_Float16)(zf - (float)h);
        }
        size_t off = (rowbase + ns) * DD + (size_t)((dg ^ ((n0 + ns) & 7)) * 8);
        *(half8*)(zh + off) = hv;
        *(half8*)(zl + off) = lv;
        sqp[ns] = sp;
    }
    #pragma unroll
    for (int k = 1; k < 8; k <<= 1) {
        #pragma unroll
        for (int ns = 0; ns < 2; ++ns) sqp[ns] += __shfl_xor(sqp[ns], k);
    }
    if (dg == 0) {
        #pragma unroll
        for (int ns = 0; ns < 2; ++ns) {
            sqv[rowbase + ns] = sqp[ns];
            nvv[rowbase + ns] = sqrtf(sqp[ns]) + EPS;
        }
    }
}

// ---------------- Stage 2: quarter-staged slab, split-fp16 MFMA, 2 blocks/CU (unchanged) ----------------
#define NORMOFS 65536
#define RSOFS   73728
#define LDSSZ_ATT 74240

__global__ __launch_bounds__(512, 2) void att8_kernel(const _Float16* __restrict__ zh,
                                                      const _Float16* __restrict__ zl,
                                                      const float* __restrict__ sqv,
                                                      const float* __restrict__ nvv,
                                                      float* __restrict__ out) {
    char* lds = dynsmem;
    const int tid  = threadIdx.x;
    const int w    = tid >> 6;
    const int lane = tid & 63;
    const int l15  = lane & 15;
    const int g    = lane >> 4;
    const int rt   = w >> 2;
    const int cg   = w & 3;
    const int t    = blockIdx.x & 31;
    const int rg   = blockIdx.x >> 5;
    const int n0   = rg * 32;
    const int qs   = rg >> 2;            // quarter containing this block's rows

    auto stage_quarter = [&](int qc, int bq, int buf) {
        const size_t slab = ((size_t)bq * TT + t) * (size_t)(NN * DD * 2);
        const char* sh = (const char*)zh + slab + qc * 16384 + tid * 16;
        const char* sl = (const char*)zl + slab + qc * 16384 + tid * 16;
        char* dh = lds + buf * 32768 + tid * 16;
        char* dl = lds + buf * 32768 + 16384 + tid * 16;
        gl_lds16(sh,        dh);
        gl_lds16(sh + 8192, dh + 8192);
        gl_lds16(sl,        dl);
        gl_lds16(sl + 8192, dl + 8192);
    };
    auto stage_norms = [&](int bn) {
        const int pb = bn & 1;
        const size_t nbyte = (((size_t)bn * TT + t) * NN) * 4;
        if (w < 2) {
            gl_lds16((const char*)nvv + nbyte + w * 1024 + lane * 16,
                     lds + NORMOFS + pb * 4096 + w * 1024 + lane * 16);
        } else if (w < 4) {
            gl_lds16((const char*)sqv + nbyte + (w - 2) * 1024 + lane * 16,
                     lds + NORMOFS + pb * 4096 + 2048 + (w - 2) * 1024 + lane * 16);
        }
    };

    stage_quarter(qs, 0, 0);
    stage_norms(0);
    __syncthreads();

    float acc[8][4];
    #pragma unroll
    for (int ct = 0; ct < 8; ++ct)
        #pragma unroll
        for (int ri = 0; ri < 4; ++ri) acc[ct][ri] = 0.f;

    half4v atth[8];
    int buf = 0;

    for (int b = 0; b < BB; ++b) {
        const int pb = b & 1;

        const int arow = n0 + rt * 16 + l15;
        const int cl   = arow & 127;
        const int ak   = arow & 7;
        half8 ah[2], al[2];
        {
            const char* ab = lds + buf * 32768;
            ah[0] = *(const half8*)(ab + cl * 128 + (((0 + g) ^ ak) << 4));
            ah[1] = *(const half8*)(ab + cl * 128 + (((4 + g) ^ ak) << 4));
            al[0] = *(const half8*)(ab + 16384 + cl * 128 + (((0 + g) ^ ak) << 4));
            al[1] = *(const half8*)(ab + 16384 + cl * 128 + (((4 + g) ^ ak) << 4));
        }

        float nr[4], sq_r[4], nri[4];
        #pragma unroll
        for (int ri = 0; ri < 4; ++ri) {
            const int rrow = n0 + rt * 16 + g * 4 + ri;
            nr[ri]   = *(const float*)(lds + NORMOFS + pb * 4096 + rrow * 4);
            sq_r[ri] = *(const float*)(lds + NORMOFS + pb * 4096 + 2048 + rrow * 4);
            nri[ri]  = __builtin_amdgcn_rcpf(nr[ri]);
        }

        float rs[4] = {0.f, 0.f, 0.f, 0.f};

        #pragma unroll
        for (int q = 0; q < 4; ++q) {
            if (q < 3)            stage_quarter((qs + q + 1) & 3, b, buf ^ 1);
            else if (b < BB - 1) { stage_quarter(qs, b + 1, buf ^ 1); stage_norms(b + 1); }

            const int qc = (qs + q) & 3;
            #pragma unroll
            for (int ct = 0; ct < 2; ++ct) {
                const int cti = q * 2 + ct;
                const int clq = cg * 32 + ct * 16 + l15;
                const int col = qc * 128 + clq;
                const int kk  = col & 7;
                const char* bbse = lds + buf * 32768;
                half8 bh0 = *(const half8*)(bbse + clq * 128 + (((0 + g) ^ kk) << 4));
                half8 bh1 = *(const half8*)(bbse + clq * 128 + (((4 + g) ^ kk) << 4));
                half8 bl0 = *(const half8*)(bbse + 16384 + clq * 128 + (((0 + g) ^ kk) << 4));
                half8 bl1 = *(const half8*)(bbse + 16384 + clq * 128 + (((4 + g) ^ kk) << 4));

                f32x4 dhh = {0.f, 0.f, 0.f, 0.f};
                f32x4 dhl = {0.f, 0.f, 0.f, 0.f};
                f32x4 dlh = {0.f, 0.f, 0.f, 0.f};
                dhh = __builtin_amdgcn_mfma_f32_16x16x32_f16(ah[0], bh0, dhh, 0, 0, 0);
                dhl = __builtin_amdgcn_mfma_f32_16x16x32_f16(ah[0], bl0, dhl, 0, 0, 0);
                dlh = __builtin_amdgcn_mfma_f32_16x16x32_f16(al[0], bh0, dlh, 0, 0, 0);
                dhh = __builtin_amdgcn_mfma_f32_16x16x32_f16(ah[1], bh1, dhh, 0, 0, 0);
                dhl = __builtin_amdgcn_mfma_f32_16x16x32_f16(ah[1], bl1, dhl, 0, 0, 0);
                dlh = __builtin_amdgcn_mfma_f32_16x16x32_f16(al[1], bh1, dlh, 0, 0, 0);
                f32x4 d = dhh + dhl + dlh;

                const float nm  = *(const float*)(lds + NORMOFS + pb * 4096 + col * 4);
                const float sqm = *(const float*)(lds + NORMOFS + pb * 4096 + 2048 + col * 4);
                const float nmi = __builtin_amdgcn_rcpf(nm);
                #pragma unroll
                for (int ri = 0; ri < 4; ++ri) {
                    float dot = d[ri];
                    float cs  = dot * nri[ri] * nmi;
                    float d2  = fmaxf(fmaf(dot, -2.f, sq_r[ri] + sqm), 0.f);
                    float dn  = __builtin_amdgcn_sqrtf(d2);
                    float a   = __expf(fmaf(dn, -__builtin_amdgcn_rcpf(nr[ri] + nm + EPS), cs));
                    atth[cti][ri] = (_Float16)a;
                    rs[ri] += a;
                }
            }

            if (q == 3) {
                #pragma unroll
                for (int ri = 0; ri < 4; ++ri) {
                    float v = rs[ri];
                    v += __shfl_xor(v, 1);
                    v += __shfl_xor(v, 2);
                    v += __shfl_xor(v, 4);
                    v += __shfl_xor(v, 8);
                    rs[ri] = v;
                }
                if (l15 == 0) {
                    #pragma unroll
                    for (int ri = 0; ri < 4; ++ri)
                        *(float*)(lds + RSOFS + ((rt * 4 + cg) * 16 + g * 4 + ri) * 4) = rs[ri];
                }
            }
            __syncthreads();
            buf ^= 1;
        }

        #pragma unroll
        for (int ri = 0; ri < 4; ++ri) {
            const int rl = g * 4 + ri;
            float tot = *(const float*)(lds + RSOFS + ((rt * 4 + 0) * 16 + rl) * 4)
                      + *(const float*)(lds + RSOFS + ((rt * 4 + 1) * 16 + rl) * 4)
                      + *(const float*)(lds + RSOFS + ((rt * 4 + 2) * 16 + rl) * 4)
                      + *(const float*)(lds + RSOFS + ((rt * 4 + 3) * 16 + rl) * 4);
            float rinv = __builtin_amdgcn_rcpf(tot + EPS);
            #pragma unroll
            for (int ct = 0; ct < 8; ++ct)
                acc[ct][ri] += (float)atth[ct][ri] * rinv;
        }
    }

    __syncthreads();
    for (int r = 0; r < 2; ++r) {
        if (rt == r) {
            #pragma unroll
            for (int ri = 0; ri < 4; ++ri)
                #pragma unroll
                for (int ct = 0; ct < 8; ++ct) {
                    const int col = ((qs + (ct >> 1)) & 3) * 128 + cg * 32 + (ct & 1) * 16 + l15;
                    *(float*)(lds + ((g * 4 + ri) * 516 + col) * 4) = acc[ct][ri] * 0.125f;
                }
        }
        __syncthreads();
        #pragma unroll
        for (int it = 0; it < 4; ++it) {
            const int idx4 = tid + it * 512;
            const int row  = idx4 >> 7;
            const int cc   = (idx4 & 127) * 4;
            float4 v = *(const float4*)(lds + (row * 516 + cc) * 4);
            *(float4*)(out + ((size_t)t * NN + n0 + r * 16 + row) * NN + cc) = v;
        }
        __syncthreads();
    }
}

extern "C" void kernel_launch(void* const* d_in, const int* in_sizes, int n_in,
                              void* d_out, int out_size, void* d_ws, size_t ws_size,
                              hipStream_t stream) {
    const float* x    = (const float*)d_in[0];
    const float* W    = (const float*)d_in[1];
    const float* bias = (const float*)d_in[2];
    float* out = (float*)d_out;

    const size_t ZELEMS = (size_t)BB * TT * NN * DD;
    const size_t NROWS  = (size_t)BB * TT * NN;
    _Float16* zh = (_Float16*)d_ws;
    _Float16* zl = zh + ZELEMS;
    float* sqv = (float*)(zh + 2 * ZELEMS);
    float* nvv = sqv + NROWS;
    float* wT  = nvv + NROWS;            // 128*64 fp32 = 32KB

    wtrans_kernel<<<dim3(1), dim3(256), 0, stream>>>(W, wT);
    z6_kernel<<<dim3(BB * (NN / 2)), dim3(256), 33792, stream>>>(x, wT, bias, zh, zl, sqv, nvv);
    att8_kernel<<<dim3(TT * (NN / 32)), dim3(512), LDSSZ_ATT, stream>>>(zh, zl, sqv, nvv, out);
}

// Round 11
// 157.282 us; speedup vs baseline: 1.0948x; 1.0948x over previous
//
#include <hip/hip_runtime.h>
#include <math.h>

#define BB 8
#define NN 512
#define FF 128
#define TT 32
#define DD 64
constexpr float EPS = 1e-6f;

typedef _Float16 half8 __attribute__((ext_vector_type(8)));
typedef _Float16 half4v __attribute__((ext_vector_type(4)));
typedef float f32x4 __attribute__((ext_vector_type(4)));

extern __shared__ char dynsmem[];

__device__ __forceinline__ float fast_tanh(float v) {
    float e = __expf(2.f * v);
    return 1.f - 2.f * __builtin_amdgcn_rcpf(e + 1.f);
}

__device__ __forceinline__ void gl_lds16(const void* g, void* l) {
    __builtin_amdgcn_global_load_lds((const __attribute__((address_space(1))) unsigned int*)g,
                                     (__attribute__((address_space(3))) unsigned int*)l,
                                     16, 0, 0);
}

// ---------------- Stage 0: transpose W[64][128] -> wT[f][d] (32KB, L1-resident for z) ----------------
__global__ __launch_bounds__(256) void wtrans_kernel(const float* __restrict__ W,
                                                     float* __restrict__ wT) {
    const int tid = threadIdx.x;
    const float4* W4 = (const float4*)W;
    #pragma unroll
    for (int it = 0; it < 8; ++it) {
        int idx4 = tid + it * 256;
        float4 w = W4[idx4];
        int d = idx4 >> 5;
        int f = (idx4 & 31) * 4;
        wT[(f + 0) * 64 + d] = w.x;
        wT[(f + 1) * 64 + d] = w.y;
        wT[(f + 2) * 64 + d] = w.z;
        wT[(f + 3) * 64 + d] = w.w;
    }
}

// ---------------- Stage 1: z = tanh(x @ W^T + b) -> fp16 hi/lo split, swizzled d-major ----------------
// z layout: [b][t][n][octet ^ (n&7)][8]
// W from global wT (L1-hot 32KB shared by co-resident blocks); LDS = xs only (33792 B) ->
// 4 blocks/CU by LDS. NO waves-per-EU arg: (256,4) and (512,4) both forced a 64-VGPR cap
// on this toolchain -> ~17MB/side scratch spill (rounds 8 & 10).
// grid: B * (N/2) = 2048 blocks, 256 threads
__global__ __launch_bounds__(256) void z7_kernel(const float* __restrict__ x,
                                                 const float* __restrict__ wT,
                                                 const float* __restrict__ bias,
                                                 _Float16* __restrict__ zh,
                                                 _Float16* __restrict__ zl,
                                                 float* __restrict__ sqv,
                                                 float* __restrict__ nvv) {
    float* xs = (float*)dynsmem;          // 2*32*132 floats
    const int tid = threadIdx.x;
    const int b  = blockIdx.x >> 8;
    const int n0 = (blockIdx.x & 255) * 2;

    const float4* x4 = (const float4*)(x + ((size_t)b * NN + n0) * FF * TT);
    #pragma unroll
    for (int it = 0; it < 8; ++it) {
        int idx4 = tid + it * 256;
        float4 v = x4[idx4];
        int e   = idx4 * 4;
        int ns  = e >> 12;
        int rem = e & 4095;
        int f   = rem >> 5;
        int t   = rem & 31;
        float* base = xs + ns * (32 * 132) + t * 132 + f;
        base[0 * 132] = v.x;
        base[1 * 132] = v.y;
        base[2 * 132] = v.z;
        base[3 * 132] = v.w;
    }
    __syncthreads();

    const int t  = tid >> 3;
    const int dg = tid & 7;
    const int d0 = dg * 8;
    float acc[2][8];
    #pragma unroll
    for (int ns = 0; ns < 2; ++ns)
        #pragma unroll
        for (int dd = 0; dd < 8; ++dd) acc[ns][dd] = 0.f;

    #pragma unroll 4
    for (int fc = 0; fc < FF; fc += 4) {
        float wv[4][8];
        #pragma unroll
        for (int k = 0; k < 4; ++k) {
            float4 a = *(const float4*)&wT[(fc + k) * 64 + d0];
            float4 c = *(const float4*)&wT[(fc + k) * 64 + d0 + 4];
            wv[k][0] = a.x; wv[k][1] = a.y; wv[k][2] = a.z; wv[k][3] = a.w;
            wv[k][4] = c.x; wv[k][5] = c.y; wv[k][6] = c.z; wv[k][7] = c.w;
        }
        #pragma unroll
        for (int ns = 0; ns < 2; ++ns) {
            float4 xv = *(const float4*)&xs[ns * (32 * 132) + t * 132 + fc];
            float xk[4] = {xv.x, xv.y, xv.z, xv.w};
            #pragma unroll
            for (int dd = 0; dd < 8; ++dd) {
                acc[ns][dd] += xk[0] * wv[0][dd] + xk[1] * wv[1][dd]
                             + xk[2] * wv[2][dd] + xk[3] * wv[3][dd];
            }
        }
    }

    float bb[8];
    #pragma unroll
    for (int dd = 0; dd < 8; ++dd) bb[dd] = bias[d0 + dd];

    const size_t rowbase = ((size_t)b * TT + t) * NN + n0;
    float sqp[2];
    #pragma unroll
    for (int ns = 0; ns < 2; ++ns) {
        half8 hv, lv;
        float sp = 0.f;
        #pragma unroll
        for (int dd = 0; dd < 8; ++dd) {
            float zf = fast_tanh(acc[ns][dd] + bb[dd]);
            sp += zf * zf;
            _Float16 h = (_Float16)zf;
            hv[dd] = h;
            lv[dd] = (_Float16)(zf - (float)h);
        }
        size_t off = (rowbase + ns) * DD + (size_t)((dg ^ ((n0 + ns) & 7)) * 8);
        *(half8*)(zh + off) = hv;
        *(half8*)(zl + off) = lv;
        sqp[ns] = sp;
    }
    #pragma unroll
    for (int k = 1; k < 8; k <<= 1) {
        #pragma unroll
        for (int ns = 0; ns < 2; ++ns) sqp[ns] += __shfl_xor(sqp[ns], k);
    }
    if (dg == 0) {
        #pragma unroll
        for (int ns = 0; ns < 2; ++ns) {
            sqv[rowbase + ns] = sqp[ns];
            nvv[rowbase + ns] = sqrtf(sqp[ns]) + EPS;
        }
    }
}

// ---------------- Stage 2: quarter-staged slab, split-fp16 MFMA, 2 blocks/CU (unchanged) ----------------
#define NORMOFS 65536
#define RSOFS   73728
#define LDSSZ_ATT 74240

__global__ __launch_bounds__(512, 2) void att8_kernel(const _Float16* __restrict__ zh,
                                                      const _Float16* __restrict__ zl,
                                                      const float* __restrict__ sqv,
                                                      const float* __restrict__ nvv,
                                                      float* __restrict__ out) {
    char* lds = dynsmem;
    const int tid  = threadIdx.x;
    const int w    = tid >> 6;
    const int lane = tid & 63;
    const int l15  = lane & 15;
    const int g    = lane >> 4;
    const int rt   = w >> 2;
    const int cg   = w & 3;
    const int t    = blockIdx.x & 31;
    const int rg   = blockIdx.x >> 5;
    const int n0   = rg * 32;
    const int qs   = rg >> 2;            // quarter containing this block's rows

    auto stage_quarter = [&](int qc, int bq, int buf) {
        const size_t slab = ((size_t)bq * TT + t) * (size_t)(NN * DD * 2);
        const char* sh = (const char*)zh + slab + qc * 16384 + tid * 16;
        const char* sl = (const char*)zl + slab + qc * 16384 + tid * 16;
        char* dh = lds + buf * 32768 + tid * 16;
        char* dl = lds + buf * 32768 + 16384 + tid * 16;
        gl_lds16(sh,        dh);
        gl_lds16(sh + 8192, dh + 8192);
        gl_lds16(sl,        dl);
        gl_lds16(sl + 8192, dl + 8192);
    };
    auto stage_norms = [&](int bn) {
        const int pb = bn & 1;
        const size_t nbyte = (((size_t)bn * TT + t) * NN) * 4;
        if (w < 2) {
            gl_lds16((const char*)nvv + nbyte + w * 1024 + lane * 16,
                     lds + NORMOFS + pb * 4096 + w * 1024 + lane * 16);
        } else if (w < 4) {
            gl_lds16((const char*)sqv + nbyte + (w - 2) * 1024 + lane * 16,
                     lds + NORMOFS + pb * 4096 + 2048 + (w - 2) * 1024 + lane * 16);
        }
    };

    stage_quarter(qs, 0, 0);
    stage_norms(0);
    __syncthreads();

    float acc[8][4];
    #pragma unroll
    for (int ct = 0; ct < 8; ++ct)
        #pragma unroll
        for (int ri = 0; ri < 4; ++ri) acc[ct][ri] = 0.f;

    half4v atth[8];
    int buf = 0;

    for (int b = 0; b < BB; ++b) {
        const int pb = b & 1;

        const int arow = n0 + rt * 16 + l15;
        const int cl   = arow & 127;
        const int ak   = arow & 7;
        half8 ah[2], al[2];
        {
            const char* ab = lds + buf * 32768;
            ah[0] = *(const half8*)(ab + cl * 128 + (((0 + g) ^ ak) << 4));
            ah[1] = *(const half8*)(ab + cl * 128 + (((4 + g) ^ ak) << 4));
            al[0] = *(const half8*)(ab + 16384 + cl * 128 + (((0 + g) ^ ak) << 4));
            al[1] = *(const half8*)(ab + 16384 + cl * 128 + (((4 + g) ^ ak) << 4));
        }

        float nr[4], sq_r[4], nri[4];
        #pragma unroll
        for (int ri = 0; ri < 4; ++ri) {
            const int rrow = n0 + rt * 16 + g * 4 + ri;
            nr[ri]   = *(const float*)(lds + NORMOFS + pb * 4096 + rrow * 4);
            sq_r[ri] = *(const float*)(lds + NORMOFS + pb * 4096 + 2048 + rrow * 4);
            nri[ri]  = __builtin_amdgcn_rcpf(nr[ri]);
        }

        float rs[4] = {0.f, 0.f, 0.f, 0.f};

        #pragma unroll
        for (int q = 0; q < 4; ++q) {
            if (q < 3)            stage_quarter((qs + q + 1) & 3, b, buf ^ 1);
            else if (b < BB - 1) { stage_quarter(qs, b + 1, buf ^ 1); stage_norms(b + 1); }

            const int qc = (qs + q) & 3;
            #pragma unroll
            for (int ct = 0; ct < 2; ++ct) {
                const int cti = q * 2 + ct;
                const int clq = cg * 32 + ct * 16 + l15;
                const int col = qc * 128 + clq;
                const int kk  = col & 7;
                const char* bbse = lds + buf * 32768;
                half8 bh0 = *(const half8*)(bbse + clq * 128 + (((0 + g) ^ kk) << 4));
                half8 bh1 = *(const half8*)(bbse + clq * 128 + (((4 + g) ^ kk) << 4));
                half8 bl0 = *(const half8*)(bbse + 16384 + clq * 128 + (((0 + g) ^ kk) << 4));
                half8 bl1 = *(const half8*)(bbse + 16384 + clq * 128 + (((4 + g) ^ kk) << 4));

                f32x4 dhh = {0.f, 0.f, 0.f, 0.f};
                f32x4 dhl = {0.f, 0.f, 0.f, 0.f};
                f32x4 dlh = {0.f, 0.f, 0.f, 0.f};
                dhh = __builtin_amdgcn_mfma_f32_16x16x32_f16(ah[0], bh0, dhh, 0, 0, 0);
                dhl = __builtin_amdgcn_mfma_f32_16x16x32_f16(ah[0], bl0, dhl, 0, 0, 0);
                dlh = __builtin_amdgcn_mfma_f32_16x16x32_f16(al[0], bh0, dlh, 0, 0, 0);
                dhh = __builtin_amdgcn_mfma_f32_16x16x32_f16(ah[1], bh1, dhh, 0, 0, 0);
                dhl = __builtin_amdgcn_mfma_f32_16x16x32_f16(ah[1], bl1, dhl, 0, 0, 0);
                dlh = __builtin_amdgcn_mfma_f32_16x16x32_f16(al[1], bh1, dlh, 0, 0, 0);
                f32x4 d = dhh + dhl + dlh;

                const float nm  = *(const float*)(lds + NORMOFS + pb * 4096 + col * 4);
                const float sqm = *(const float*)(lds + NORMOFS + pb * 4096 + 2048 + col * 4);
                const float nmi = __builtin_amdgcn_rcpf(nm);
                #pragma unroll
                for (int ri = 0; ri < 4; ++ri) {
                    float dot = d[ri];
                    float cs  = dot * nri[ri] * nmi;
                    float d2  = fmaxf(fmaf(dot, -2.f, sq_r[ri] + sqm), 0.f);
                    float dn  = __builtin_amdgcn_sqrtf(d2);
                    float a   = __expf(fmaf(dn, -__builtin_amdgcn_rcpf(nr[ri] + nm + EPS), cs));
                    atth[cti][ri] = (_Float16)a;
                    rs[ri] += a;
                }
            }

            if (q == 3) {
                #pragma unroll
                for (int ri = 0; ri < 4; ++ri) {
                    float v = rs[ri];
                    v += __shfl_xor(v, 1);
                    v += __shfl_xor(v, 2);
                    v += __shfl_xor(v, 4);
                    v += __shfl_xor(v, 8);
                    rs[ri] = v;
                }
                if (l15 == 0) {
                    #pragma unroll
                    for (int ri = 0; ri < 4; ++ri)
                        *(float*)(lds + RSOFS + ((rt * 4 + cg) * 16 + g * 4 + ri) * 4) = rs[ri];
                }
            }
            __syncthreads();
            buf ^= 1;
        }

        #pragma unroll
        for (int ri = 0; ri < 4; ++ri) {
            const int rl = g * 4 + ri;
            float tot = *(const float*)(lds + RSOFS + ((rt * 4 + 0) * 16 + rl) * 4)
                      + *(const float*)(lds + RSOFS + ((rt * 4 + 1) * 16 + rl) * 4)
                      + *(const float*)(lds + RSOFS + ((rt * 4 + 2) * 16 + rl) * 4)
                      + *(const float*)(lds + RSOFS + ((rt * 4 + 3) * 16 + rl) * 4);
            float rinv = __builtin_amdgcn_rcpf(tot + EPS);
            #pragma unroll
            for (int ct = 0; ct < 8; ++ct)
                acc[ct][ri] += (float)atth[ct][ri] * rinv;
        }
    }

    __syncthreads();
    for (int r = 0; r < 2; ++r) {
        if (rt == r) {
            #pragma unroll
            for (int ri = 0; ri < 4; ++ri)
                #pragma unroll
                for (int ct = 0; ct < 8; ++ct) {
                    const int col = ((qs + (ct >> 1)) & 3) * 128 + cg * 32 + (ct & 1) * 16 + l15;
                    *(float*)(lds + ((g * 4 + ri) * 516 + col) * 4) = acc[ct][ri] * 0.125f;
                }
        }
        __syncthreads();
        #pragma unroll
        for (int it = 0; it < 4; ++it) {
            const int idx4 = tid + it * 512;
            const int row  = idx4 >> 7;
            const int cc   = (idx4 & 127) * 4;
            float4 v = *(const float4*)(lds + (row * 516 + cc) * 4);
            *(float4*)(out + ((size_t)t * NN + n0 + r * 16 + row) * NN + cc) = v;
        }
        __syncthreads();
    }
}

extern "C" void kernel_launch(void* const* d_in, const int* in_sizes, int n_in,
                              void* d_out, int out_size, void* d_ws, size_t ws_size,
                              hipStream_t stream) {
    const float* x    = (const float*)d_in[0];
    const float* W    = (const float*)d_in[1];
    const float* bias = (const float*)d_in[2];
    float* out = (float*)d_out;

    const size_t ZELEMS = (size_t)BB * TT * NN * DD;
    const size_t NROWS  = (size_t)BB * TT * NN;
    _Float16* zh = (_Float16*)d_ws;
    _Float16* zl = zh + ZELEMS;
    float* sqv = (float*)(zh + 2 * ZELEMS);
    float* nvv = sqv + NROWS;
    float* wT  = nvv + NROWS;            // 128*64 fp32 = 32KB

    wtrans_kernel<<<dim3(1), dim3(256), 0, stream>>>(W, wT);
    z7_kernel<<<dim3(BB * (NN / 2)), dim3(256), 33792, stream>>>(x, wT, bias, zh, zl, sqv, nvv);
    att8_kernel<<<dim3(TT * (NN / 32)), dim3(512), LDSSZ_ATT, stream>>>(zh, zl, sqv, nvv, out);
}

// Round 12
// 122.551 us; speedup vs baseline: 1.4051x; 1.2834x over previous
//
#include <hip/hip_runtime.h>
#include <math.h>

#define BB 8
#define NN 512
#define FF 128
#define TT 32
#define DD 64
constexpr float EPS = 1e-6f;

typedef _Float16 half8 __attribute__((ext_vector_type(8)));
typedef _Float16 half4v __attribute__((ext_vector_type(4)));
typedef float f32x4 __attribute__((ext_vector_type(4)));

extern __shared__ char dynsmem[];

__device__ __forceinline__ float fast_tanh(float v) {
    float e = __expf(2.f * v);
    return 1.f - 2.f * __builtin_amdgcn_rcpf(e + 1.f);
}

__device__ __forceinline__ void gl_lds16(const void* g, void* l) {
    __builtin_amdgcn_global_load_lds((const __attribute__((address_space(1))) unsigned int*)g,
                                     (__attribute__((address_space(3))) unsigned int*)l,
                                     16, 0, 0);
}

// ---------------- Stage 0: split W into MFMA-fragment-layout fp16 hi/lo tables ----------------
// whF/wlF[(s*4+dt)*64 + l15*4 + g] : half8 = W[(dt*16+l15)][s*32+g*8 .. +8] hi/lo
__global__ __launch_bounds__(256) void wsplit_kernel(const float* __restrict__ W,
                                                     _Float16* __restrict__ whF,
                                                     _Float16* __restrict__ wlF) {
    const int tid = threadIdx.x;
    #pragma unroll
    for (int k = 0; k < 4; ++k) {
        int u   = tid + k * 256;          // 0..1023
        int g   = u & 3;
        int l15 = (u >> 2) & 15;
        int sd  = u >> 6;                 // s*4+dt
        int s   = sd >> 2;
        int dt  = sd & 3;
        const float* src = W + (dt * 16 + l15) * 128 + s * 32 + g * 8;
        half8 hv, lv;
        #pragma unroll
        for (int i = 0; i < 8; ++i) {
            float f = src[i];
            hv[i] = (_Float16)f;
            lv[i] = (_Float16)(f - (float)hv[i]);
        }
        ((half8*)whF)[u] = hv;
        ((half8*)wlF)[u] = lv;
    }
}

// ---------------- Stage 1: z = tanh(x @ W^T + b) via split-fp16 MFMA ----------------
// grid: B * (N/4) = 1024 blocks, 256 threads = 4 waves; wave w computes n = n0+w.
// Per wave: rows = t (2 tiles), cols = d (4 tiles), K = f (4 k-steps); acc fp32.
// Output layout identical to before: zh/zl[b][t][n][oct ^ (n&7)][8] + sqv/nvv.
__global__ __launch_bounds__(256) void z8_kernel(const float* __restrict__ x,
                                                 const _Float16* __restrict__ whF,
                                                 const _Float16* __restrict__ wlF,
                                                 const float* __restrict__ bias,
                                                 _Float16* __restrict__ zh,
                                                 _Float16* __restrict__ zl,
                                                 float* __restrict__ sqv,
                                                 float* __restrict__ nvv) {
    float* xs = (float*)dynsmem;          // 4 waves x 32 t x 132 f (padded)
    const int tid = threadIdx.x;
    const int b  = blockIdx.x >> 7;
    const int n0 = (blockIdx.x & 127) * 4;

    // stage x[b][n0..n0+3][F][T] (16384 floats) -> xs[ns][t][f]
    const float4* x4 = (const float4*)(x + ((size_t)b * NN + n0) * FF * TT);
    #pragma unroll
    for (int it = 0; it < 16; ++it) {
        int idx4 = tid + it * 256;
        float4 v = x4[idx4];
        int e   = idx4 * 4;
        int ns  = e >> 12;
        int rem = e & 4095;
        int f   = rem >> 5;
        int t   = rem & 31;
        float* base = xs + ns * 4224 + t * 132 + f;
        base[0 * 132] = v.x;
        base[1 * 132] = v.y;
        base[2 * 132] = v.z;
        base[3 * 132] = v.w;
    }
    __syncthreads();

    const int w    = tid >> 6;
    const int lane = tid & 63;
    const int l15  = lane & 15;
    const int g    = lane >> 4;
    const int n    = n0 + w;
    float* xs_w = xs + w * 4224;

    // W-hi fragments resident in registers (16 x half8 = 64 VGPR), from L1-hot 16KB table
    half8 wh[16];
    #pragma unroll
    for (int sd = 0; sd < 16; ++sd)
        wh[sd] = ((const half8*)whF)[sd * 64 + l15 * 4 + g];

    float bb[4];
    #pragma unroll
    for (int dt = 0; dt < 4; ++dt) bb[dt] = bias[dt * 16 + l15];

    f32x4 acc[4][2];
    #pragma unroll
    for (int dt = 0; dt < 4; ++dt)
        #pragma unroll
        for (int tt = 0; tt < 2; ++tt) acc[dt][tt] = f32x4{0.f, 0.f, 0.f, 0.f};

    #pragma unroll
    for (int s = 0; s < 4; ++s) {
        // A fragments: x rows t, k = s*32+g*8..+8, fp32 -> fp16 hi/lo in-reg
        half8 ah[2], al[2];
        #pragma unroll
        for (int tt = 0; tt < 2; ++tt) {
            const float* ap = xs_w + (tt * 16 + l15) * 132 + s * 32 + g * 8;
            float4 p0 = *(const float4*)ap;
            float4 p1 = *(const float4*)(ap + 4);
            float fv[8] = {p0.x, p0.y, p0.z, p0.w, p1.x, p1.y, p1.z, p1.w};
            #pragma unroll
            for (int i = 0; i < 8; ++i) {
                ah[tt][i] = (_Float16)fv[i];
                al[tt][i] = (_Float16)(fv[i] - (float)ah[tt][i]);
            }
        }
        #pragma unroll
        for (int dt = 0; dt < 4; ++dt) {
            half8 wl_ = ((const half8*)wlF)[(s * 4 + dt) * 64 + l15 * 4 + g];
            acc[dt][0] = __builtin_amdgcn_mfma_f32_16x16x32_f16(ah[0], wh[s * 4 + dt], acc[dt][0], 0, 0, 0);
            acc[dt][1] = __builtin_amdgcn_mfma_f32_16x16x32_f16(ah[1], wh[s * 4 + dt], acc[dt][1], 0, 0, 0);
            acc[dt][0] = __builtin_amdgcn_mfma_f32_16x16x32_f16(al[0], wh[s * 4 + dt], acc[dt][0], 0, 0, 0);
            acc[dt][1] = __builtin_amdgcn_mfma_f32_16x16x32_f16(al[1], wh[s * 4 + dt], acc[dt][1], 0, 0, 0);
            acc[dt][0] = __builtin_amdgcn_mfma_f32_16x16x32_f16(ah[0], wl_, acc[dt][0], 0, 0, 0);
            acc[dt][1] = __builtin_amdgcn_mfma_f32_16x16x32_f16(ah[1], wl_, acc[dt][1], 0, 0, 0);
        }
    }

    // bias + tanh in regs, bounce through wave-private LDS (reuse xs_w; in-order LDS per wave,
    // no barrier needed), stride 68 floats (16B-aligned, low-conflict)
    float* zsw = xs_w;
    #pragma unroll
    for (int dt = 0; dt < 4; ++dt)
        #pragma unroll
        for (int tt = 0; tt < 2; ++tt)
            #pragma unroll
            for (int ri = 0; ri < 4; ++ri) {
                float zf = fast_tanh(acc[dt][tt][ri] + bb[dt]);
                zsw[(tt * 16 + g * 4 + ri) * 68 + dt * 16 + l15] = zf;
            }

    // readback: lane -> (t = lane>>1, 4 octets), pack fp16 hi/lo, swizzled global store + sq
    const int tr = lane >> 1;
    const int ob = (lane & 1) * 4;
    const size_t rowidx = ((size_t)b * TT + tr) * NN + n;
    _Float16* zhp = zh + rowidx * DD;
    _Float16* zlp = zl + rowidx * DD;
    float sqp = 0.f;
    #pragma unroll
    for (int j = 0; j < 4; ++j) {
        int oct = ob + j;
        const float* qp = zsw + tr * 68 + oct * 8;
        float4 q0 = *(const float4*)qp;
        float4 q1 = *(const float4*)(qp + 4);
        float fv[8] = {q0.x, q0.y, q0.z, q0.w, q1.x, q1.y, q1.z, q1.w};
        half8 hv, lv;
        #pragma unroll
        for (int i = 0; i < 8; ++i) {
            sqp += fv[i] * fv[i];
            hv[i] = (_Float16)fv[i];
            lv[i] = (_Float16)(fv[i] - (float)hv[i]);
        }
        const int so = (oct ^ (n & 7)) * 8;
        *(half8*)(zhp + so) = hv;
        *(half8*)(zlp + so) = lv;
    }
    float sqf = sqp + __shfl_xor(sqp, 1);
    if (!(lane & 1)) {
        sqv[rowidx] = sqf;
        nvv[rowidx] = sqrtf(sqf) + EPS;
    }
}

// ---------------- Stage 2: quarter-staged slab, split-fp16 MFMA, 2 blocks/CU (unchanged) ----------------
#define NORMOFS 65536
#define RSOFS   73728
#define LDSSZ_ATT 74240

__global__ __launch_bounds__(512, 2) void att8_kernel(const _Float16* __restrict__ zh,
                                                      const _Float16* __restrict__ zl,
                                                      const float* __restrict__ sqv,
                                                      const float* __restrict__ nvv,
                                                      float* __restrict__ out) {
    char* lds = dynsmem;
    const int tid  = threadIdx.x;
    const int w    = tid >> 6;
    const int lane = tid & 63;
    const int l15  = lane & 15;
    const int g    = lane >> 4;
    const int rt   = w >> 2;
    const int cg   = w & 3;
    const int t    = blockIdx.x & 31;
    const int rg   = blockIdx.x >> 5;
    const int n0   = rg * 32;
    const int qs   = rg >> 2;            // quarter containing this block's rows

    auto stage_quarter = [&](int qc, int bq, int buf) {
        const size_t slab = ((size_t)bq * TT + t) * (size_t)(NN * DD * 2);
        const char* sh = (const char*)zh + slab + qc * 16384 + tid * 16;
        const char* sl = (const char*)zl + slab + qc * 16384 + tid * 16;
        char* dh = lds + buf * 32768 + tid * 16;
        char* dl = lds + buf * 32768 + 16384 + tid * 16;
        gl_lds16(sh,        dh);
        gl_lds16(sh + 8192, dh + 8192);
        gl_lds16(sl,        dl);
        gl_lds16(sl + 8192, dl + 8192);
    };
    auto stage_norms = [&](int bn) {
        const int pb = bn & 1;
        const size_t nbyte = (((size_t)bn * TT + t) * NN) * 4;
        if (w < 2) {
            gl_lds16((const char*)nvv + nbyte + w * 1024 + lane * 16,
                     lds + NORMOFS + pb * 4096 + w * 1024 + lane * 16);
        } else if (w < 4) {
            gl_lds16((const char*)sqv + nbyte + (w - 2) * 1024 + lane * 16,
                     lds + NORMOFS + pb * 4096 + 2048 + (w - 2) * 1024 + lane * 16);
        }
    };

    stage_quarter(qs, 0, 0);
    stage_norms(0);
    __syncthreads();

    float acc[8][4];
    #pragma unroll
    for (int ct = 0; ct < 8; ++ct)
        #pragma unroll
        for (int ri = 0; ri < 4; ++ri) acc[ct][ri] = 0.f;

    half4v atth[8];
    int buf = 0;

    for (int b = 0; b < BB; ++b) {
        const int pb = b & 1;

        const int arow = n0 + rt * 16 + l15;
        const int cl   = arow & 127;
        const int ak   = arow & 7;
        half8 ah[2], al[2];
        {
            const char* ab = lds + buf * 32768;
            ah[0] = *(const half8*)(ab + cl * 128 + (((0 + g) ^ ak) << 4));
            ah[1] = *(const half8*)(ab + cl * 128 + (((4 + g) ^ ak) << 4));
            al[0] = *(const half8*)(ab + 16384 + cl * 128 + (((0 + g) ^ ak) << 4));
            al[1] = *(const half8*)(ab + 16384 + cl * 128 + (((4 + g) ^ ak) << 4));
        }

        float nr[4], sq_r[4], nri[4];
        #pragma unroll
        for (int ri = 0; ri < 4; ++ri) {
            const int rrow = n0 + rt * 16 + g * 4 + ri;
            nr[ri]   = *(const float*)(lds + NORMOFS + pb * 4096 + rrow * 4);
            sq_r[ri] = *(const float*)(lds + NORMOFS + pb * 4096 + 2048 + rrow * 4);
            nri[ri]  = __builtin_amdgcn_rcpf(nr[ri]);
        }

        float rs[4] = {0.f, 0.f, 0.f, 0.f};

        #pragma unroll
        for (int q = 0; q < 4; ++q) {
            if (q < 3)            stage_quarter((qs + q + 1) & 3, b, buf ^ 1);
            else if (b < BB - 1) { stage_quarter(qs, b + 1, buf ^ 1); stage_norms(b + 1); }

            const int qc = (qs + q) & 3;
            #pragma unroll
            for (int ct = 0; ct < 2; ++ct) {
                const int cti = q * 2 + ct;
                const int clq = cg * 32 + ct * 16 + l15;
                const int col = qc * 128 + clq;
                const int kk  = col & 7;
                const char* bbse = lds + buf * 32768;
                half8 bh0 = *(const half8*)(bbse + clq * 128 + (((0 + g) ^ kk) << 4));
                half8 bh1 = *(const half8*)(bbse + clq * 128 + (((4 + g) ^ kk) << 4));
                half8 bl0 = *(const half8*)(bbse + 16384 + clq * 128 + (((0 + g) ^ kk) << 4));
                half8 bl1 = *(const half8*)(bbse + 16384 + clq * 128 + (((4 + g) ^ kk) << 4));

                f32x4 dhh = {0.f, 0.f, 0.f, 0.f};
                f32x4 dhl = {0.f, 0.f, 0.f, 0.f};
                f32x4 dlh = {0.f, 0.f, 0.f, 0.f};
                dhh = __builtin_amdgcn_mfma_f32_16x16x32_f16(ah[0], bh0, dhh, 0, 0, 0);
                dhl = __builtin_amdgcn_mfma_f32_16x16x32_f16(ah[0], bl0, dhl, 0, 0, 0);
                dlh = __builtin_amdgcn_mfma_f32_16x16x32_f16(al[0], bh0, dlh, 0, 0, 0);
                dhh = __builtin_amdgcn_mfma_f32_16x16x32_f16(ah[1], bh1, dhh, 0, 0, 0);
                dhl = __builtin_amdgcn_mfma_f32_16x16x32_f16(ah[1], bl1, dhl, 0, 0, 0);
                dlh = __builtin_amdgcn_mfma_f32_16x16x32_f16(al[1], bh1, dlh, 0, 0, 0);
                f32x4 d = dhh + dhl + dlh;

                const float nm  = *(const float*)(lds + NORMOFS + pb * 4096 + col * 4);
                const float sqm = *(const float*)(lds + NORMOFS + pb * 4096 + 2048 + col * 4);
                const float nmi = __builtin_amdgcn_rcpf(nm);
                #pragma unroll
                for (int ri = 0; ri < 4; ++ri) {
                    float dot = d[ri];
                    float cs  = dot * nri[ri] * nmi;
                    float d2  = fmaxf(fmaf(dot, -2.f, sq_r[ri] + sqm), 0.f);
                    float dn  = __builtin_amdgcn_sqrtf(d2);
                    float a   = __expf(fmaf(dn, -__builtin_amdgcn_rcpf(nr[ri] + nm + EPS), cs));
                    atth[cti][ri] = (_Float16)a;
                    rs[ri] += a;
                }
            }

            if (q == 3) {
                #pragma unroll
                for (int ri = 0; ri < 4; ++ri) {
                    float v = rs[ri];
                    v += __shfl_xor(v, 1);
                    v += __shfl_xor(v, 2);
                    v += __shfl_xor(v, 4);
                    v += __shfl_xor(v, 8);
                    rs[ri] = v;
                }
                if (l15 == 0) {
                    #pragma unroll
                    for (int ri = 0; ri < 4; ++ri)
                        *(float*)(lds + RSOFS + ((rt * 4 + cg) * 16 + g * 4 + ri) * 4) = rs[ri];
                }
            }
            __syncthreads();
            buf ^= 1;
        }

        #pragma unroll
        for (int ri = 0; ri < 4; ++ri) {
            const int rl = g * 4 + ri;
            float tot = *(const float*)(lds + RSOFS + ((rt * 4 + 0) * 16 + rl) * 4)
                      + *(const float*)(lds + RSOFS + ((rt * 4 + 1) * 16 + rl) * 4)
                      + *(const float*)(lds + RSOFS + ((rt * 4 + 2) * 16 + rl) * 4)
                      + *(const float*)(lds + RSOFS + ((rt * 4 + 3) * 16 + rl) * 4);
            float rinv = __builtin_amdgcn_rcpf(tot + EPS);
            #pragma unroll
            for (int ct = 0; ct < 8; ++ct)
                acc[ct][ri] += (float)atth[ct][ri] * rinv;
        }
    }

    __syncthreads();
    for (int r = 0; r < 2; ++r) {
        if (rt == r) {
            #pragma unroll
            for (int ri = 0; ri < 4; ++ri)
                #pragma unroll
                for (int ct = 0; ct < 8; ++ct) {
                    const int col = ((qs + (ct >> 1)) & 3) * 128 + cg * 32 + (ct & 1) * 16 + l15;
                    *(float*)(lds + ((g * 4 + ri) * 516 + col) * 4) = acc[ct][ri] * 0.125f;
                }
        }
        __syncthreads();
        #pragma unroll
        for (int it = 0; it < 4; ++it) {
            const int idx4 = tid + it * 512;
            const int row  = idx4 >> 7;
            const int cc   = (idx4 & 127) * 4;
            float4 v = *(const float4*)(lds + (row * 516 + cc) * 4);
            *(float4*)(out + ((size_t)t * NN + n0 + r * 16 + row) * NN + cc) = v;
        }
        __syncthreads();
    }
}

extern "C" void kernel_launch(void* const* d_in, const int* in_sizes, int n_in,
                              void* d_out, int out_size, void* d_ws, size_t ws_size,
                              hipStream_t stream) {
    const float* x    = (const float*)d_in[0];
    const float* W    = (const float*)d_in[1];
    const float* bias = (const float*)d_in[2];
    float* out = (float*)d_out;

    const size_t ZELEMS = (size_t)BB * TT * NN * DD;
    const size_t NROWS  = (size_t)BB * TT * NN;
    _Float16* zh = (_Float16*)d_ws;
    _Float16* zl = zh + ZELEMS;
    float* sqv = (float*)(zh + 2 * ZELEMS);
    float* nvv = sqv + NROWS;
    _Float16* whF = (_Float16*)(nvv + NROWS);   // 8192 halves (16KB)
    _Float16* wlF = whF + 8192;                 // 8192 halves (16KB)

    wsplit_kernel<<<dim3(1), dim3(256), 0, stream>>>(W, whF, wlF);
    z8_kernel<<<dim3(BB * (NN / 4)), dim3(256), 67584, stream>>>(x, whF, wlF, bias, zh, zl, sqv, nvv);
    att8_kernel<<<dim3(TT * (NN / 32)), dim3(512), LDSSZ_ATT, stream>>>(zh, zl, sqv, nvv, out);
}

// Round 13
// 120.099 us; speedup vs baseline: 1.4338x; 1.0204x over previous
//
#include <hip/hip_runtime.h>
#include <math.h>

#define BB 8
#define NN 512
#define FF 128
#define TT 32
#define DD 64
constexpr float EPS = 1e-6f;

typedef _Float16 half8 __attribute__((ext_vector_type(8)));
typedef float f32x4 __attribute__((ext_vector_type(4)));

extern __shared__ char dynsmem[];

__device__ __forceinline__ float fast_tanh(float v) {
    float e = __expf(2.f * v);
    return 1.f - 2.f * __builtin_amdgcn_rcpf(e + 1.f);
}

__device__ __forceinline__ void gl_lds16(const void* g, void* l) {
    __builtin_amdgcn_global_load_lds((const __attribute__((address_space(1))) unsigned int*)g,
                                     (__attribute__((address_space(3))) unsigned int*)l,
                                     16, 0, 0);
}

// ---------------- Stage 0: split W into MFMA-fragment-layout fp16 hi/lo tables ----------------
__global__ __launch_bounds__(256) void wsplit_kernel(const float* __restrict__ W,
                                                     _Float16* __restrict__ whF,
                                                     _Float16* __restrict__ wlF) {
    const int tid = threadIdx.x;
    #pragma unroll
    for (int k = 0; k < 4; ++k) {
        int u   = tid + k * 256;          // 0..1023
        int g   = u & 3;
        int l15 = (u >> 2) & 15;
        int sd  = u >> 6;                 // s*4+dt
        int s   = sd >> 2;
        int dt  = sd & 3;
        const float* src = W + (dt * 16 + l15) * 128 + s * 32 + g * 8;
        half8 hv, lv;
        #pragma unroll
        for (int i = 0; i < 8; ++i) {
            float f = src[i];
            hv[i] = (_Float16)f;
            lv[i] = (_Float16)(f - (float)hv[i]);
        }
        ((half8*)whF)[u] = hv;
        ((half8*)wlF)[u] = lv;
    }
}

// ---------------- Stage 1: z = tanh(x @ W^T + b) via split-fp16 MFMA ----------------
__global__ __launch_bounds__(256) void z8_kernel(const float* __restrict__ x,
                                                 const _Float16* __restrict__ whF,
                                                 const _Float16* __restrict__ wlF,
                                                 const float* __restrict__ bias,
                                                 _Float16* __restrict__ zh,
                                                 _Float16* __restrict__ zl,
                                                 float* __restrict__ sqv,
                                                 float* __restrict__ nvv) {
    float* xs = (float*)dynsmem;          // 4 waves x 32 t x 132 f (padded)
    const int tid = threadIdx.x;
    const int b  = blockIdx.x >> 7;
    const int n0 = (blockIdx.x & 127) * 4;

    const float4* x4 = (const float4*)(x + ((size_t)b * NN + n0) * FF * TT);
    #pragma unroll
    for (int it = 0; it < 16; ++it) {
        int idx4 = tid + it * 256;
        float4 v = x4[idx4];
        int e   = idx4 * 4;
        int ns  = e >> 12;
        int rem = e & 4095;
        int f   = rem >> 5;
        int t   = rem & 31;
        float* base = xs + ns * 4224 + t * 132 + f;
        base[0 * 132] = v.x;
        base[1 * 132] = v.y;
        base[2 * 132] = v.z;
        base[3 * 132] = v.w;
    }
    __syncthreads();

    const int w    = tid >> 6;
    const int lane = tid & 63;
    const int l15  = lane & 15;
    const int g    = lane >> 4;
    const int n    = n0 + w;
    float* xs_w = xs + w * 4224;

    half8 wh[16];
    #pragma unroll
    for (int sd = 0; sd < 16; ++sd)
        wh[sd] = ((const half8*)whF)[sd * 64 + l15 * 4 + g];

    float bb[4];
    #pragma unroll
    for (int dt = 0; dt < 4; ++dt) bb[dt] = bias[dt * 16 + l15];

    f32x4 acc[4][2];
    #pragma unroll
    for (int dt = 0; dt < 4; ++dt)
        #pragma unroll
        for (int tt = 0; tt < 2; ++tt) acc[dt][tt] = f32x4{0.f, 0.f, 0.f, 0.f};

    #pragma unroll
    for (int s = 0; s < 4; ++s) {
        half8 ah[2], al[2];
        #pragma unroll
        for (int tt = 0; tt < 2; ++tt) {
            const float* ap = xs_w + (tt * 16 + l15) * 132 + s * 32 + g * 8;
            float4 p0 = *(const float4*)ap;
            float4 p1 = *(const float4*)(ap + 4);
            float fv[8] = {p0.x, p0.y, p0.z, p0.w, p1.x, p1.y, p1.z, p1.w};
            #pragma unroll
            for (int i = 0; i < 8; ++i) {
                ah[tt][i] = (_Float16)fv[i];
                al[tt][i] = (_Float16)(fv[i] - (float)ah[tt][i]);
            }
        }
        #pragma unroll
        for (int dt = 0; dt < 4; ++dt) {
            half8 wl_ = ((const half8*)wlF)[(s * 4 + dt) * 64 + l15 * 4 + g];
            acc[dt][0] = __builtin_amdgcn_mfma_f32_16x16x32_f16(ah[0], wh[s * 4 + dt], acc[dt][0], 0, 0, 0);
            acc[dt][1] = __builtin_amdgcn_mfma_f32_16x16x32_f16(ah[1], wh[s * 4 + dt], acc[dt][1], 0, 0, 0);
            acc[dt][0] = __builtin_amdgcn_mfma_f32_16x16x32_f16(al[0], wh[s * 4 + dt], acc[dt][0], 0, 0, 0);
            acc[dt][1] = __builtin_amdgcn_mfma_f32_16x16x32_f16(al[1], wh[s * 4 + dt], acc[dt][1], 0, 0, 0);
            acc[dt][0] = __builtin_amdgcn_mfma_f32_16x16x32_f16(ah[0], wl_, acc[dt][0], 0, 0, 0);
            acc[dt][1] = __builtin_amdgcn_mfma_f32_16x16x32_f16(ah[1], wl_, acc[dt][1], 0, 0, 0);
        }
    }

    float* zsw = xs_w;
    #pragma unroll
    for (int dt = 0; dt < 4; ++dt)
        #pragma unroll
        for (int tt = 0; tt < 2; ++tt)
            #pragma unroll
            for (int ri = 0; ri < 4; ++ri) {
                float zf = fast_tanh(acc[dt][tt][ri] + bb[dt]);
                zsw[(tt * 16 + g * 4 + ri) * 68 + dt * 16 + l15] = zf;
            }

    const int tr = lane >> 1;
    const int ob = (lane & 1) * 4;
    const size_t rowidx = ((size_t)b * TT + tr) * NN + n;
    _Float16* zhp = zh + rowidx * DD;
    _Float16* zlp = zl + rowidx * DD;
    float sqp = 0.f;
    #pragma unroll
    for (int j = 0; j < 4; ++j) {
        int oct = ob + j;
        const float* qp = zsw + tr * 68 + oct * 8;
        float4 q0 = *(const float4*)qp;
        float4 q1 = *(const float4*)(qp + 4);
        float fv[8] = {q0.x, q0.y, q0.z, q0.w, q1.x, q1.y, q1.z, q1.w};
        half8 hv, lv;
        #pragma unroll
        for (int i = 0; i < 8; ++i) {
            sqp += fv[i] * fv[i];
            hv[i] = (_Float16)fv[i];
            lv[i] = (_Float16)(fv[i] - (float)hv[i]);
        }
        const int so = (oct ^ (n & 7)) * 8;
        *(half8*)(zhp + so) = hv;
        *(half8*)(zlp + so) = lv;
    }
    float sqf = sqp + __shfl_xor(sqp, 1);
    if (!(lane & 1)) {
        sqv[rowidx] = sqf;
        nvv[rowidx] = sqrtf(sqf) + EPS;
    }
}

// ---------------- Stage 2: quarter-staged slab, split-fp16 MFMA, epilogue diet ----------------
#define NORMOFS 65536
#define RSOFS   73728
#define LDSSZ_ATT 74240

__global__ __launch_bounds__(512, 2) void att9_kernel(const _Float16* __restrict__ zh,
                                                      const _Float16* __restrict__ zl,
                                                      const float* __restrict__ sqv,
                                                      const float* __restrict__ nvv,
                                                      float* __restrict__ out) {
    char* lds = dynsmem;
    const int tid  = threadIdx.x;
    const int w    = tid >> 6;
    const int lane = tid & 63;
    const int l15  = lane & 15;
    const int g    = lane >> 4;
    const int rt   = w >> 2;
    const int cg   = w & 3;
    const int t    = blockIdx.x & 31;
    const int rg   = blockIdx.x >> 5;
    const int n0   = rg * 32;
    const int qs   = rg >> 2;

    auto stage_quarter = [&](int qc, int bq, int buf) {
        const size_t slab = ((size_t)bq * TT + t) * (size_t)(NN * DD * 2);
        const char* sh = (const char*)zh + slab + qc * 16384 + tid * 16;
        const char* sl = (const char*)zl + slab + qc * 16384 + tid * 16;
        char* dh = lds + buf * 32768 + tid * 16;
        char* dl = lds + buf * 32768 + 16384 + tid * 16;
        gl_lds16(sh,        dh);
        gl_lds16(sh + 8192, dh + 8192);
        gl_lds16(sl,        dl);
        gl_lds16(sl + 8192, dl + 8192);
    };
    auto stage_norms = [&](int bn) {
        const int pb = bn & 1;
        const size_t nbyte = (((size_t)bn * TT + t) * NN) * 4;
        if (w < 2) {
            gl_lds16((const char*)nvv + nbyte + w * 1024 + lane * 16,
                     lds + NORMOFS + pb * 4096 + w * 1024 + lane * 16);
        } else if (w < 4) {
            gl_lds16((const char*)sqv + nbyte + (w - 2) * 1024 + lane * 16,
                     lds + NORMOFS + pb * 4096 + 2048 + (w - 2) * 1024 + lane * 16);
        }
    };

    stage_quarter(qs, 0, 0);
    stage_norms(0);
    __syncthreads();

    float acc[8][4];
    #pragma unroll
    for (int ct = 0; ct < 8; ++ct)
        #pragma unroll
        for (int ri = 0; ri < 4; ++ri) acc[ct][ri] = 0.f;

    float att_f[8][4];
    int buf = 0;

    for (int b = 0; b < BB; ++b) {
        const int pb = b & 1;

        const int arow = n0 + rt * 16 + l15;
        const int cl   = arow & 127;
        const int ak   = arow & 7;
        half8 ah[2], al[2];
        {
            const char* ab = lds + buf * 32768;
            ah[0] = *(const half8*)(ab + cl * 128 + (((0 + g) ^ ak) << 4));
            ah[1] = *(const half8*)(ab + cl * 128 + (((4 + g) ^ ak) << 4));
            al[0] = *(const half8*)(ab + 16384 + cl * 128 + (((0 + g) ^ ak) << 4));
            al[1] = *(const half8*)(ab + 16384 + cl * 128 + (((4 + g) ^ ak) << 4));
        }

        // per-b row constants: nrE = nr+EPS (for sum-norm), nri = 1/nr
        float nrE[4], sq_r[4], nri[4];
        #pragma unroll
        for (int ri = 0; ri < 4; ++ri) {
            const int rrow = n0 + rt * 16 + g * 4 + ri;
            float nr = *(const float*)(lds + NORMOFS + pb * 4096 + rrow * 4);
            sq_r[ri] = *(const float*)(lds + NORMOFS + pb * 4096 + 2048 + rrow * 4);
            nri[ri]  = __builtin_amdgcn_rcpf(nr);
            nrE[ri]  = nr + EPS;
        }

        float rs[4] = {0.f, 0.f, 0.f, 0.f};

        #pragma unroll
        for (int q = 0; q < 4; ++q) {
            if (q < 3)            stage_quarter((qs + q + 1) & 3, b, buf ^ 1);
            else if (b < BB - 1) { stage_quarter(qs, b + 1, buf ^ 1); stage_norms(b + 1); }

            const int qc = (qs + q) & 3;
            #pragma unroll
            for (int ct = 0; ct < 2; ++ct) {
                const int cti = q * 2 + ct;
                const int clq = cg * 32 + ct * 16 + l15;
                const int col = qc * 128 + clq;
                const int kk  = col & 7;
                const char* bbse = lds + buf * 32768;
                half8 bh0 = *(const half8*)(bbse + clq * 128 + (((0 + g) ^ kk) << 4));
                half8 bh1 = *(const half8*)(bbse + clq * 128 + (((4 + g) ^ kk) << 4));
                half8 bl0 = *(const half8*)(bbse + 16384 + clq * 128 + (((0 + g) ^ kk) << 4));
                half8 bl1 = *(const half8*)(bbse + 16384 + clq * 128 + (((4 + g) ^ kk) << 4));

                f32x4 dhh = {0.f, 0.f, 0.f, 0.f};
                f32x4 dhl = {0.f, 0.f, 0.f, 0.f};
                f32x4 dlh = {0.f, 0.f, 0.f, 0.f};
                dhh = __builtin_amdgcn_mfma_f32_16x16x32_f16(ah[0], bh0, dhh, 0, 0, 0);
                dhl = __builtin_amdgcn_mfma_f32_16x16x32_f16(ah[0], bl0, dhl, 0, 0, 0);
                dlh = __builtin_amdgcn_mfma_f32_16x16x32_f16(al[0], bh0, dlh, 0, 0, 0);
                dhh = __builtin_amdgcn_mfma_f32_16x16x32_f16(ah[1], bh1, dhh, 0, 0, 0);
                dhl = __builtin_amdgcn_mfma_f32_16x16x32_f16(ah[1], bl1, dhl, 0, 0, 0);
                dlh = __builtin_amdgcn_mfma_f32_16x16x32_f16(al[1], bh1, dlh, 0, 0, 0);
                f32x4 d = dhh + dhl + dlh;

                const float nm  = *(const float*)(lds + NORMOFS + pb * 4096 + col * 4);
                const float sqm = *(const float*)(lds + NORMOFS + pb * 4096 + 2048 + col * 4);
                const float nmi = __builtin_amdgcn_rcpf(nm);
                // per-ct hoists (amortized over 4 elems): pr, s2, rc
                float pr[4], s2[4], rc[4];
                #pragma unroll
                for (int ri = 0; ri < 4; ++ri) {
                    pr[ri] = nri[ri] * nmi;
                    s2[ri] = sq_r[ri] + sqm;
                    rc[ri] = __builtin_amdgcn_rcpf(nrE[ri] + nm);
                }
                #pragma unroll
                for (int ri = 0; ri < 4; ++ri) {
                    float dot = d[ri];
                    float cs  = dot * pr[ri];
                    float d2  = fmaxf(fmaf(dot, -2.f, s2[ri]), 0.f);
                    float dn  = __builtin_amdgcn_sqrtf(d2);
                    float a   = __expf(fmaf(dn, -rc[ri], cs));
                    att_f[cti][ri] = a;
                    rs[ri] += a;
                }
            }

            if (q == 3) {
                #pragma unroll
                for (int ri = 0; ri < 4; ++ri) {
                    float v = rs[ri];
                    v += __shfl_xor(v, 1);
                    v += __shfl_xor(v, 2);
                    v += __shfl_xor(v, 4);
                    v += __shfl_xor(v, 8);
                    rs[ri] = v;
                }
                if (l15 == 0) {
                    #pragma unroll
                    for (int ri = 0; ri < 4; ++ri)
                        *(float*)(lds + RSOFS + ((rt * 4 + cg) * 16 + g * 4 + ri) * 4) = rs[ri];
                }
            }
            __syncthreads();
            buf ^= 1;
        }

        #pragma unroll
        for (int ri = 0; ri < 4; ++ri) {
            const int rl = g * 4 + ri;
            float tot = *(const float*)(lds + RSOFS + ((rt * 4 + 0) * 16 + rl) * 4)
                      + *(const float*)(lds + RSOFS + ((rt * 4 + 1) * 16 + rl) * 4)
                      + *(const float*)(lds + RSOFS + ((rt * 4 + 2) * 16 + rl) * 4)
                      + *(const float*)(lds + RSOFS + ((rt * 4 + 3) * 16 + rl) * 4);
            float rinv = __builtin_amdgcn_rcpf(tot + EPS);
            #pragma unroll
            for (int ct = 0; ct < 8; ++ct)
                acc[ct][ri] += att_f[ct][ri] * rinv;
        }
    }

    __syncthreads();
    for (int r = 0; r < 2; ++r) {
        if (rt == r) {
            #pragma unroll
            for (int ri = 0; ri < 4; ++ri)
                #pragma unroll
                for (int ct = 0; ct < 8; ++ct) {
                    const int col = ((qs + (ct >> 1)) & 3) * 128 + cg * 32 + (ct & 1) * 16 + l15;
                    *(float*)(lds + ((g * 4 + ri) * 516 + col) * 4) = acc[ct][ri] * 0.125f;
                }
        }
        __syncthreads();
        #pragma unroll
        for (int it = 0; it < 4; ++it) {
            const int idx4 = tid + it * 512;
            const int row  = idx4 >> 7;
            const int cc   = (idx4 & 127) * 4;
            float4 v = *(const float4*)(lds + (row * 516 + cc) * 4);
            *(float4*)(out + ((size_t)t * NN + n0 + r * 16 + row) * NN + cc) = v;
        }
        __syncthreads();
    }
}

extern "C" void kernel_launch(void* const* d_in, const int* in_sizes, int n_in,
                              void* d_out, int out_size, void* d_ws, size_t ws_size,
                              hipStream_t stream) {
    const float* x    = (const float*)d_in[0];
    const float* W    = (const float*)d_in[1];
    const float* bias = (const float*)d_in[2];
    float* out = (float*)d_out;

    const size_t ZELEMS = (size_t)BB * TT * NN * DD;
    const size_t NROWS  = (size_t)BB * TT * NN;
    _Float16* zh = (_Float16*)d_ws;
    _Float16* zl = zh + ZELEMS;
    float* sqv = (float*)(zh + 2 * ZELEMS);
    float* nvv = sqv + NROWS;
    _Float16* whF = (_Float16*)(nvv + NROWS);   // 16KB
    _Float16* wlF = whF + 8192;                 // 16KB

    wsplit_kernel<<<dim3(1), dim3(256), 0, stream>>>(W, whF, wlF);
    z8_kernel<<<dim3(BB * (NN / 4)), dim3(256), 67584, stream>>>(x, whF, wlF, bias, zh, zl, sqv, nvv);
    att9_kernel<<<dim3(TT * (NN / 32)), dim3(512), LDSSZ_ATT, stream>>>(zh, zl, sqv, nvv, out);
}

// Round 14
// 109.370 us; speedup vs baseline: 1.5744x; 1.0981x over previous
//
#include <hip/hip_runtime.h>
#include <math.h>

#define BB 8
#define NN 512
#define FF 128
#define TT 32
#define DD 64
constexpr float EPS = 1e-6f;

typedef _Float16 half8 __attribute__((ext_vector_type(8)));
typedef float f32x4 __attribute__((ext_vector_type(4)));

extern __shared__ char dynsmem[];

__device__ __forceinline__ float fast_tanh(float v) {
    float e = __expf(2.f * v);
    return 1.f - 2.f * __builtin_amdgcn_rcpf(e + 1.f);
}

__device__ __forceinline__ void gl_lds16(const void* g, void* l) {
    __builtin_amdgcn_global_load_lds((const __attribute__((address_space(1))) unsigned int*)g,
                                     (__attribute__((address_space(3))) unsigned int*)l,
                                     16, 0, 0);
}

// ---------------- Stage 0: split W into MFMA-fragment-layout fp16 hi/lo tables ----------------
__global__ __launch_bounds__(256) void wsplit_kernel(const float* __restrict__ W,
                                                     _Float16* __restrict__ whF,
                                                     _Float16* __restrict__ wlF) {
    const int tid = threadIdx.x;
    #pragma unroll
    for (int k = 0; k < 4; ++k) {
        int u   = tid + k * 256;          // 0..1023
        int g   = u & 3;
        int l15 = (u >> 2) & 15;
        int sd  = u >> 6;                 // s*4+dt
        int s   = sd >> 2;
        int dt  = sd & 3;
        const float* src = W + (dt * 16 + l15) * 128 + s * 32 + g * 8;
        half8 hv, lv;
        #pragma unroll
        for (int i = 0; i < 8; ++i) {
            float f = src[i];
            hv[i] = (_Float16)f;
            lv[i] = (_Float16)(f - (float)hv[i]);
        }
        ((half8*)whF)[u] = hv;
        ((half8*)wlF)[u] = lv;
    }
}

// ---------------- Stage 1: z = tanh(x @ W^T + b) via split-fp16 MFMA (unchanged) ----------------
__global__ __launch_bounds__(256) void z8_kernel(const float* __restrict__ x,
                                                 const _Float16* __restrict__ whF,
                                                 const _Float16* __restrict__ wlF,
                                                 const float* __restrict__ bias,
                                                 _Float16* __restrict__ zh,
                                                 _Float16* __restrict__ zl,
                                                 float* __restrict__ sqv,
                                                 float* __restrict__ nvv) {
    float* xs = (float*)dynsmem;          // 4 waves x 32 t x 132 f (padded)
    const int tid = threadIdx.x;
    const int b  = blockIdx.x >> 7;
    const int n0 = (blockIdx.x & 127) * 4;

    const float4* x4 = (const float4*)(x + ((size_t)b * NN + n0) * FF * TT);
    #pragma unroll
    for (int it = 0; it < 16; ++it) {
        int idx4 = tid + it * 256;
        float4 v = x4[idx4];
        int e   = idx4 * 4;
        int ns  = e >> 12;
        int rem = e & 4095;
        int f   = rem >> 5;
        int t   = rem & 31;
        float* base = xs + ns * 4224 + t * 132 + f;
        base[0 * 132] = v.x;
        base[1 * 132] = v.y;
        base[2 * 132] = v.z;
        base[3 * 132] = v.w;
    }
    __syncthreads();

    const int w    = tid >> 6;
    const int lane = tid & 63;
    const int l15  = lane & 15;
    const int g    = lane >> 4;
    const int n    = n0 + w;
    float* xs_w = xs + w * 4224;

    half8 wh[16];
    #pragma unroll
    for (int sd = 0; sd < 16; ++sd)
        wh[sd] = ((const half8*)whF)[sd * 64 + l15 * 4 + g];

    float bb[4];
    #pragma unroll
    for (int dt = 0; dt < 4; ++dt) bb[dt] = bias[dt * 16 + l15];

    f32x4 acc[4][2];
    #pragma unroll
    for (int dt = 0; dt < 4; ++dt)
        #pragma unroll
        for (int tt = 0; tt < 2; ++tt) acc[dt][tt] = f32x4{0.f, 0.f, 0.f, 0.f};

    #pragma unroll
    for (int s = 0; s < 4; ++s) {
        half8 ah[2], al[2];
        #pragma unroll
        for (int tt = 0; tt < 2; ++tt) {
            const float* ap = xs_w + (tt * 16 + l15) * 132 + s * 32 + g * 8;
            float4 p0 = *(const float4*)ap;
            float4 p1 = *(const float4*)(ap + 4);
            float fv[8] = {p0.x, p0.y, p0.z, p0.w, p1.x, p1.y, p1.z, p1.w};
            #pragma unroll
            for (int i = 0; i < 8; ++i) {
                ah[tt][i] = (_Float16)fv[i];
                al[tt][i] = (_Float16)(fv[i] - (float)ah[tt][i]);
            }
        }
        #pragma unroll
        for (int dt = 0; dt < 4; ++dt) {
            half8 wl_ = ((const half8*)wlF)[(s * 4 + dt) * 64 + l15 * 4 + g];
            acc[dt][0] = __builtin_amdgcn_mfma_f32_16x16x32_f16(ah[0], wh[s * 4 + dt], acc[dt][0], 0, 0, 0);
            acc[dt][1] = __builtin_amdgcn_mfma_f32_16x16x32_f16(ah[1], wh[s * 4 + dt], acc[dt][1], 0, 0, 0);
            acc[dt][0] = __builtin_amdgcn_mfma_f32_16x16x32_f16(al[0], wh[s * 4 + dt], acc[dt][0], 0, 0, 0);
            acc[dt][1] = __builtin_amdgcn_mfma_f32_16x16x32_f16(al[1], wh[s * 4 + dt], acc[dt][1], 0, 0, 0);
            acc[dt][0] = __builtin_amdgcn_mfma_f32_16x16x32_f16(ah[0], wl_, acc[dt][0], 0, 0, 0);
            acc[dt][1] = __builtin_amdgcn_mfma_f32_16x16x32_f16(ah[1], wl_, acc[dt][1], 0, 0, 0);
        }
    }

    float* zsw = xs_w;
    #pragma unroll
    for (int dt = 0; dt < 4; ++dt)
        #pragma unroll
        for (int tt = 0; tt < 2; ++tt)
            #pragma unroll
            for (int ri = 0; ri < 4; ++ri) {
                float zf = fast_tanh(acc[dt][tt][ri] + bb[dt]);
                zsw[(tt * 16 + g * 4 + ri) * 68 + dt * 16 + l15] = zf;
            }

    const int tr = lane >> 1;
    const int ob = (lane & 1) * 4;
    const size_t rowidx = ((size_t)b * TT + tr) * NN + n;
    _Float16* zhp = zh + rowidx * DD;
    _Float16* zlp = zl + rowidx * DD;
    float sqp = 0.f;
    #pragma unroll
    for (int j = 0; j < 4; ++j) {
        int oct = ob + j;
        const float* qp = zsw + tr * 68 + oct * 8;
        float4 q0 = *(const float4*)qp;
        float4 q1 = *(const float4*)(qp + 4);
        float fv[8] = {q0.x, q0.y, q0.z, q0.w, q1.x, q1.y, q1.z, q1.w};
        half8 hv, lv;
        #pragma unroll
        for (int i = 0; i < 8; ++i) {
            sqp += fv[i] * fv[i];
            hv[i] = (_Float16)fv[i];
            lv[i] = (_Float16)(fv[i] - (float)hv[i]);
        }
        const int so = (oct ^ (n & 7)) * 8;
        *(half8*)(zhp + so) = hv;
        *(half8*)(zlp + so) = lv;
    }
    float sqf = sqp + __shfl_xor(sqp, 1);
    if (!(lane & 1)) {
        sqv[rowidx] = sqf;
        nvv[rowidx] = sqrtf(sqf) + EPS;
    }
}

// ---------------- Stage 2: B-single split (S = (Ah+Al)·Bh^T), zh-only staging ----------------
// LDS: dbuf 2 x zh-quarter 16K | norms[2][nv 2K + sq 2K] | rs[2][4][16]
#define NORMOFS 32768
#define RSOFS   40960
#define LDSSZ_ATT 41472

__global__ __launch_bounds__(512, 2) void att10_kernel(const _Float16* __restrict__ zh,
                                                       const _Float16* __restrict__ zl,
                                                       const float* __restrict__ sqv,
                                                       const float* __restrict__ nvv,
                                                       float* __restrict__ out) {
    char* lds = dynsmem;
    const int tid  = threadIdx.x;
    const int w    = tid >> 6;
    const int lane = tid & 63;
    const int l15  = lane & 15;
    const int g    = lane >> 4;
    const int rt   = w >> 2;
    const int cg   = w & 3;
    const int t    = blockIdx.x & 31;
    const int rg   = blockIdx.x >> 5;
    const int n0   = rg * 32;
    const int qs   = rg >> 2;

    auto stage_quarter = [&](int qc, int bq, int buf) {
        const size_t slab = ((size_t)bq * TT + t) * (size_t)(NN * DD * 2);
        const char* sh = (const char*)zh + slab + qc * 16384 + tid * 16;
        char* dh = lds + buf * 16384 + tid * 16;
        gl_lds16(sh,        dh);
        gl_lds16(sh + 8192, dh + 8192);
    };
    auto stage_norms = [&](int bn) {
        const int pb = bn & 1;
        const size_t nbyte = (((size_t)bn * TT + t) * NN) * 4;
        if (w < 2) {
            gl_lds16((const char*)nvv + nbyte + w * 1024 + lane * 16,
                     lds + NORMOFS + pb * 4096 + w * 1024 + lane * 16);
        } else if (w < 4) {
            gl_lds16((const char*)sqv + nbyte + (w - 2) * 1024 + lane * 16,
                     lds + NORMOFS + pb * 4096 + 2048 + (w - 2) * 1024 + lane * 16);
        }
    };

    stage_quarter(qs, 0, 0);
    stage_norms(0);
    __syncthreads();

    float acc[8][4];
    #pragma unroll
    for (int ct = 0; ct < 8; ++ct)
        #pragma unroll
        for (int ri = 0; ri < 4; ++ri) acc[ct][ri] = 0.f;

    float att_f[8][4];
    int buf = 0;

    for (int b = 0; b < BB; ++b) {
        const int pb = b & 1;

        const int arow = n0 + rt * 16 + l15;
        const int cl   = arow & 127;
        const int ak   = arow & 7;
        // Al from global (zl not staged), Ah from LDS own quarter
        half8 ah[2], al[2];
        {
            const size_t ro = (((size_t)b * TT + t) * NN + arow) * DD;
            al[0] = *(const half8*)(zl + ro + ((g ^ ak) * 8));
            al[1] = *(const half8*)(zl + ro + (((4 + g) ^ ak) * 8));
            const char* ab = lds + buf * 16384;
            ah[0] = *(const half8*)(ab + cl * 128 + ((g ^ ak) << 4));
            ah[1] = *(const half8*)(ab + cl * 128 + (((4 + g) ^ ak) << 4));
        }

        float nrE[4], sq_r[4], nri[4];
        #pragma unroll
        for (int ri = 0; ri < 4; ++ri) {
            const int rrow = n0 + rt * 16 + g * 4 + ri;
            float nr = *(const float*)(lds + NORMOFS + pb * 4096 + rrow * 4);
            sq_r[ri] = *(const float*)(lds + NORMOFS + pb * 4096 + 2048 + rrow * 4);
            nri[ri]  = __builtin_amdgcn_rcpf(nr);
            nrE[ri]  = nr + EPS;
        }

        float rs[4] = {0.f, 0.f, 0.f, 0.f};

        #pragma unroll
        for (int q = 0; q < 4; ++q) {
            if (q < 3)            stage_quarter((qs + q + 1) & 3, b, buf ^ 1);
            else if (b < BB - 1) { stage_quarter(qs, b + 1, buf ^ 1); stage_norms(b + 1); }

            const int qc = (qs + q) & 3;
            #pragma unroll
            for (int ct = 0; ct < 2; ++ct) {
                const int cti = q * 2 + ct;
                const int clq = cg * 32 + ct * 16 + l15;
                const int col = qc * 128 + clq;
                const int kk  = col & 7;
                const char* bbse = lds + buf * 16384;
                half8 bh0 = *(const half8*)(bbse + clq * 128 + (((0 + g) ^ kk) << 4));
                half8 bh1 = *(const half8*)(bbse + clq * 128 + (((4 + g) ^ kk) << 4));

                // 2 independent 2-deep chains: (Ah+Al) . Bh
                f32x4 c0 = {0.f, 0.f, 0.f, 0.f};
                f32x4 c1 = {0.f, 0.f, 0.f, 0.f};
                c0 = __builtin_amdgcn_mfma_f32_16x16x32_f16(ah[0], bh0, c0, 0, 0, 0);
                c1 = __builtin_amdgcn_mfma_f32_16x16x32_f16(ah[1], bh1, c1, 0, 0, 0);
                c0 = __builtin_amdgcn_mfma_f32_16x16x32_f16(al[0], bh0, c0, 0, 0, 0);
                c1 = __builtin_amdgcn_mfma_f32_16x16x32_f16(al[1], bh1, c1, 0, 0, 0);
                f32x4 d = c0 + c1;

                const float nm  = *(const float*)(lds + NORMOFS + pb * 4096 + col * 4);
                const float sqm = *(const float*)(lds + NORMOFS + pb * 4096 + 2048 + col * 4);
                const float nmi = __builtin_amdgcn_rcpf(nm);
                float pr[4], s2[4], rc[4];
                #pragma unroll
                for (int ri = 0; ri < 4; ++ri) {
                    pr[ri] = nri[ri] * nmi;
                    s2[ri] = sq_r[ri] + sqm;
                    rc[ri] = __builtin_amdgcn_rcpf(nrE[ri] + nm);
                }
                #pragma unroll
                for (int ri = 0; ri < 4; ++ri) {
                    float dot = d[ri];
                    float cs  = dot * pr[ri];
                    float d2  = fmaxf(fmaf(dot, -2.f, s2[ri]), 0.f);
                    float dn  = __builtin_amdgcn_sqrtf(d2);
                    float a   = __expf(fmaf(dn, -rc[ri], cs));
                    att_f[cti][ri] = a;
                    rs[ri] += a;
                }
            }

            if (q == 3) {
                #pragma unroll
                for (int ri = 0; ri < 4; ++ri) {
                    float v = rs[ri];
                    v += __shfl_xor(v, 1);
                    v += __shfl_xor(v, 2);
                    v += __shfl_xor(v, 4);
                    v += __shfl_xor(v, 8);
                    rs[ri] = v;
                }
                if (l15 == 0) {
                    #pragma unroll
                    for (int ri = 0; ri < 4; ++ri)
                        *(float*)(lds + RSOFS + ((rt * 4 + cg) * 16 + g * 4 + ri) * 4) = rs[ri];
                }
            }
            __syncthreads();
            buf ^= 1;
        }

        #pragma unroll
        for (int ri = 0; ri < 4; ++ri) {
            const int rl = g * 4 + ri;
            float tot = *(const float*)(lds + RSOFS + ((rt * 4 + 0) * 16 + rl) * 4)
                      + *(const float*)(lds + RSOFS + ((rt * 4 + 1) * 16 + rl) * 4)
                      + *(const float*)(lds + RSOFS + ((rt * 4 + 2) * 16 + rl) * 4)
                      + *(const float*)(lds + RSOFS + ((rt * 4 + 3) * 16 + rl) * 4);
            float rinv = __builtin_amdgcn_rcpf(tot + EPS);
            #pragma unroll
            for (int ct = 0; ct < 8; ++ct)
                acc[ct][ri] += att_f[ct][ri] * rinv;
        }
    }

    __syncthreads();
    for (int r = 0; r < 2; ++r) {
        if (rt == r) {
            #pragma unroll
            for (int ri = 0; ri < 4; ++ri)
                #pragma unroll
                for (int ct = 0; ct < 8; ++ct) {
                    const int col = ((qs + (ct >> 1)) & 3) * 128 + cg * 32 + (ct & 1) * 16 + l15;
                    *(float*)(lds + ((g * 4 + ri) * 516 + col) * 4) = acc[ct][ri] * 0.125f;
                }
        }
        __syncthreads();
        #pragma unroll
        for (int it = 0; it < 4; ++it) {
            const int idx4 = tid + it * 512;
            const int row  = idx4 >> 7;
            const int cc   = (idx4 & 127) * 4;
            float4 v = *(const float4*)(lds + (row * 516 + cc) * 4);
            *(float4*)(out + ((size_t)t * NN + n0 + r * 16 + row) * NN + cc) = v;
        }
        __syncthreads();
    }
}

extern "C" void kernel_launch(void* const* d_in, const int* in_sizes, int n_in,
                              void* d_out, int out_size, void* d_ws, size_t ws_size,
                              hipStream_t stream) {
    const float* x    = (const float*)d_in[0];
    const float* W    = (const float*)d_in[1];
    const float* bias = (const float*)d_in[2];
    float* out = (float*)d_out;

    const size_t ZELEMS = (size_t)BB * TT * NN * DD;
    const size_t NROWS  = (size_t)BB * TT * NN;
    _Float16* zh = (_Float16*)d_ws;
    _Float16* zl = zh + ZELEMS;
    float* sqv = (float*)(zh + 2 * ZELEMS);
    float* nvv = sqv + NROWS;
    _Float16* whF = (_Float16*)(nvv + NROWS);   // 16KB
    _Float16* wlF = whF + 8192;                 // 16KB

    wsplit_kernel<<<dim3(1), dim3(256), 0, stream>>>(W, whF, wlF);
    z8_kernel<<<dim3(BB * (NN / 4)), dim3(256), 67584, stream>>>(x, whF, wlF, bias, zh, zl, sqv, nvv);
    att10_kernel<<<dim3(TT * (NN / 32)), dim3(512), LDSSZ_ATT, stream>>>(zh, zl, sqv, nvv, out);
}

// Round 15
// 107.985 us; speedup vs baseline: 1.5946x; 1.0128x over previous
//
#include <hip/hip_runtime.h>
#include <math.h>

#define BB 8
#define NN 512
#define FF 128
#define TT 32
#define DD 64
constexpr float EPS = 1e-6f;

typedef _Float16 half8 __attribute__((ext_vector_type(8)));
typedef float f32x4 __attribute__((ext_vector_type(4)));

extern __shared__ char dynsmem[];

__device__ __forceinline__ float fast_tanh(float v) {
    float e = __expf(2.f * v);
    return 1.f - 2.f * __builtin_amdgcn_rcpf(e + 1.f);
}

__device__ __forceinline__ void gl_lds16(const void* g, void* l) {
    __builtin_amdgcn_global_load_lds((const __attribute__((address_space(1))) unsigned int*)g,
                                     (__attribute__((address_space(3))) unsigned int*)l,
                                     16, 0, 0);
}

// ---------------- Stage 0: split W into MFMA-fragment-layout fp16 hi/lo tables ----------------
__global__ __launch_bounds__(256) void wsplit_kernel(const float* __restrict__ W,
                                                     _Float16* __restrict__ whF,
                                                     _Float16* __restrict__ wlF) {
    const int tid = threadIdx.x;
    #pragma unroll
    for (int k = 0; k < 4; ++k) {
        int u   = tid + k * 256;          // 0..1023
        int g   = u & 3;
        int l15 = (u >> 2) & 15;
        int sd  = u >> 6;                 // s*4+dt
        int s   = sd >> 2;
        int dt  = sd & 3;
        const float* src = W + (dt * 16 + l15) * 128 + s * 32 + g * 8;
        half8 hv, lv;
        #pragma unroll
        for (int i = 0; i < 8; ++i) {
            float f = src[i];
            hv[i] = (_Float16)f;
            lv[i] = (_Float16)(f - (float)hv[i]);
        }
        ((half8*)whF)[u] = hv;
        ((half8*)wlF)[u] = lv;
    }
}

// ---------------- Stage 1: z = tanh(x @ W^T + b) via split-fp16 MFMA (unchanged) ----------------
__global__ __launch_bounds__(256) void z8_kernel(const float* __restrict__ x,
                                                 const _Float16* __restrict__ whF,
                                                 const _Float16* __restrict__ wlF,
                                                 const float* __restrict__ bias,
                                                 _Float16* __restrict__ zh,
                                                 _Float16* __restrict__ zl,
                                                 float* __restrict__ sqv,
                                                 float* __restrict__ nvv) {
    float* xs = (float*)dynsmem;          // 4 waves x 32 t x 132 f (padded)
    const int tid = threadIdx.x;
    const int b  = blockIdx.x >> 7;
    const int n0 = (blockIdx.x & 127) * 4;

    const float4* x4 = (const float4*)(x + ((size_t)b * NN + n0) * FF * TT);
    #pragma unroll
    for (int it = 0; it < 16; ++it) {
        int idx4 = tid + it * 256;
        float4 v = x4[idx4];
        int e   = idx4 * 4;
        int ns  = e >> 12;
        int rem = e & 4095;
        int f   = rem >> 5;
        int t   = rem & 31;
        float* base = xs + ns * 4224 + t * 132 + f;
        base[0 * 132] = v.x;
        base[1 * 132] = v.y;
        base[2 * 132] = v.z;
        base[3 * 132] = v.w;
    }
    __syncthreads();

    const int w    = tid >> 6;
    const int lane = tid & 63;
    const int l15  = lane & 15;
    const int g    = lane >> 4;
    const int n    = n0 + w;
    float* xs_w = xs + w * 4224;

    half8 wh[16];
    #pragma unroll
    for (int sd = 0; sd < 16; ++sd)
        wh[sd] = ((const half8*)whF)[sd * 64 + l15 * 4 + g];

    float bb[4];
    #pragma unroll
    for (int dt = 0; dt < 4; ++dt) bb[dt] = bias[dt * 16 + l15];

    f32x4 acc[4][2];
    #pragma unroll
    for (int dt = 0; dt < 4; ++dt)
        #pragma unroll
        for (int tt = 0; tt < 2; ++tt) acc[dt][tt] = f32x4{0.f, 0.f, 0.f, 0.f};

    #pragma unroll
    for (int s = 0; s < 4; ++s) {
        half8 ah[2], al[2];
        #pragma unroll
        for (int tt = 0; tt < 2; ++tt) {
            const float* ap = xs_w + (tt * 16 + l15) * 132 + s * 32 + g * 8;
            float4 p0 = *(const float4*)ap;
            float4 p1 = *(const float4*)(ap + 4);
            float fv[8] = {p0.x, p0.y, p0.z, p0.w, p1.x, p1.y, p1.z, p1.w};
            #pragma unroll
            for (int i = 0; i < 8; ++i) {
                ah[tt][i] = (_Float16)fv[i];
                al[tt][i] = (_Float16)(fv[i] - (float)ah[tt][i]);
            }
        }
        #pragma unroll
        for (int dt = 0; dt < 4; ++dt) {
            half8 wl_ = ((const half8*)wlF)[(s * 4 + dt) * 64 + l15 * 4 + g];
            acc[dt][0] = __builtin_amdgcn_mfma_f32_16x16x32_f16(ah[0], wh[s * 4 + dt], acc[dt][0], 0, 0, 0);
            acc[dt][1] = __builtin_amdgcn_mfma_f32_16x16x32_f16(ah[1], wh[s * 4 + dt], acc[dt][1], 0, 0, 0);
            acc[dt][0] = __builtin_amdgcn_mfma_f32_16x16x32_f16(al[0], wh[s * 4 + dt], acc[dt][0], 0, 0, 0);
            acc[dt][1] = __builtin_amdgcn_mfma_f32_16x16x32_f16(al[1], wh[s * 4 + dt], acc[dt][1], 0, 0, 0);
            acc[dt][0] = __builtin_amdgcn_mfma_f32_16x16x32_f16(ah[0], wl_, acc[dt][0], 0, 0, 0);
            acc[dt][1] = __builtin_amdgcn_mfma_f32_16x16x32_f16(ah[1], wl_, acc[dt][1], 0, 0, 0);
        }
    }

    float* zsw = xs_w;
    #pragma unroll
    for (int dt = 0; dt < 4; ++dt)
        #pragma unroll
        for (int tt = 0; tt < 2; ++tt)
            #pragma unroll
            for (int ri = 0; ri < 4; ++ri) {
                float zf = fast_tanh(acc[dt][tt][ri] + bb[dt]);
                zsw[(tt * 16 + g * 4 + ri) * 68 + dt * 16 + l15] = zf;
            }

    const int tr = lane >> 1;
    const int ob = (lane & 1) * 4;
    const size_t rowidx = ((size_t)b * TT + tr) * NN + n;
    _Float16* zhp = zh + rowidx * DD;
    _Float16* zlp = zl + rowidx * DD;
    float sqp = 0.f;
    #pragma unroll
    for (int j = 0; j < 4; ++j) {
        int oct = ob + j;
        const float* qp = zsw + tr * 68 + oct * 8;
        float4 q0 = *(const float4*)qp;
        float4 q1 = *(const float4*)(qp + 4);
        float fv[8] = {q0.x, q0.y, q0.z, q0.w, q1.x, q1.y, q1.z, q1.w};
        half8 hv, lv;
        #pragma unroll
        for (int i = 0; i < 8; ++i) {
            sqp += fv[i] * fv[i];
            hv[i] = (_Float16)fv[i];
            lv[i] = (_Float16)(fv[i] - (float)hv[i]);
        }
        const int so = (oct ^ (n & 7)) * 8;
        *(half8*)(zhp + so) = hv;
        *(half8*)(zlp + so) = lv;
    }
    float sqf = sqp + __shfl_xor(sqp, 1);
    if (!(lane & 1)) {
        sqv[rowidx] = sqf;
        nvv[rowidx] = sqrtf(sqf) + EPS;
    }
}

// ---------------- Stage 2: half-slab staging (2 phases/b), B-single split ----------------
// LDS: dbuf 2 x zh-half 32K | norms[2][nv 2K + sq 2K] | rs[2][4][16]
#define NORMOFS 65536
#define RSOFS   73728
#define LDSSZ_ATT 74240

__global__ __launch_bounds__(512, 2) void att11_kernel(const _Float16* __restrict__ zh,
                                                       const _Float16* __restrict__ zl,
                                                       const float* __restrict__ sqv,
                                                       const float* __restrict__ nvv,
                                                       float* __restrict__ out) {
    char* lds = dynsmem;
    const int tid  = threadIdx.x;
    const int w    = tid >> 6;
    const int lane = tid & 63;
    const int l15  = lane & 15;
    const int g    = lane >> 4;
    const int rt   = w >> 2;
    const int cg   = w & 3;
    const int t    = blockIdx.x & 31;
    const int rg   = blockIdx.x >> 5;
    const int n0   = rg * 32;
    const int hs   = rg >> 3;            // half (0/1) containing this block's rows

    auto stage_half = [&](int hc, int bq, int buf) {
        const size_t slab = ((size_t)bq * TT + t) * (size_t)(NN * DD * 2);
        const char* sh = (const char*)zh + slab + hc * 32768 + tid * 16;
        char* dh = lds + buf * 32768 + tid * 16;
        gl_lds16(sh,         dh);
        gl_lds16(sh + 8192,  dh + 8192);
        gl_lds16(sh + 16384, dh + 16384);
        gl_lds16(sh + 24576, dh + 24576);
    };
    auto stage_norms = [&](int bn) {
        const int pb = bn & 1;
        const size_t nbyte = (((size_t)bn * TT + t) * NN) * 4;
        if (w < 2) {
            gl_lds16((const char*)nvv + nbyte + w * 1024 + lane * 16,
                     lds + NORMOFS + pb * 4096 + w * 1024 + lane * 16);
        } else if (w < 4) {
            gl_lds16((const char*)sqv + nbyte + (w - 2) * 1024 + lane * 16,
                     lds + NORMOFS + pb * 4096 + 2048 + (w - 2) * 1024 + lane * 16);
        }
    };

    stage_half(hs, 0, 0);
    stage_norms(0);
    __syncthreads();

    float acc[8][4];
    #pragma unroll
    for (int ct = 0; ct < 8; ++ct)
        #pragma unroll
        for (int ri = 0; ri < 4; ++ri) acc[ct][ri] = 0.f;

    float att_f[8][4];
    int buf = 0;

    for (int b = 0; b < BB; ++b) {
        const int pb = b & 1;

        const int arow = n0 + rt * 16 + l15;
        const int cl   = arow & 255;      // row within own half
        const int ak   = arow & 7;
        // Al from global (zl not staged), Ah from LDS own half
        half8 ah[2], al[2];
        {
            const size_t ro = (((size_t)b * TT + t) * NN + arow) * DD;
            al[0] = *(const half8*)(zl + ro + ((g ^ ak) * 8));
            al[1] = *(const half8*)(zl + ro + (((4 + g) ^ ak) * 8));
            const char* ab = lds + buf * 32768;
            ah[0] = *(const half8*)(ab + cl * 128 + ((g ^ ak) << 4));
            ah[1] = *(const half8*)(ab + cl * 128 + (((4 + g) ^ ak) << 4));
        }

        float nrE[4], sq_r[4], nri[4];
        #pragma unroll
        for (int ri = 0; ri < 4; ++ri) {
            const int rrow = n0 + rt * 16 + g * 4 + ri;
            float nr = *(const float*)(lds + NORMOFS + pb * 4096 + rrow * 4);
            sq_r[ri] = *(const float*)(lds + NORMOFS + pb * 4096 + 2048 + rrow * 4);
            nri[ri]  = __builtin_amdgcn_rcpf(nr);
            nrE[ri]  = nr + EPS;
        }

        float rs[4] = {0.f, 0.f, 0.f, 0.f};

        #pragma unroll
        for (int p = 0; p < 2; ++p) {
            if (p == 0)           stage_half(hs ^ 1, b, buf ^ 1);
            else if (b < BB - 1) { stage_half(hs, b + 1, buf ^ 1); stage_norms(b + 1); }

            const int hc = hs ^ p;
            #pragma unroll
            for (int ct = 0; ct < 4; ++ct) {
                const int cti = p * 4 + ct;
                const int clq = cg * 64 + ct * 16 + l15;   // col within half (0..255)
                const int col = hc * 256 + clq;
                const int kk  = col & 7;
                const char* bbse = lds + buf * 32768;
                half8 bh0 = *(const half8*)(bbse + clq * 128 + (((0 + g) ^ kk) << 4));
                half8 bh1 = *(const half8*)(bbse + clq * 128 + (((4 + g) ^ kk) << 4));

                f32x4 c0 = {0.f, 0.f, 0.f, 0.f};
                f32x4 c1 = {0.f, 0.f, 0.f, 0.f};
                c0 = __builtin_amdgcn_mfma_f32_16x16x32_f16(ah[0], bh0, c0, 0, 0, 0);
                c1 = __builtin_amdgcn_mfma_f32_16x16x32_f16(ah[1], bh1, c1, 0, 0, 0);
                c0 = __builtin_amdgcn_mfma_f32_16x16x32_f16(al[0], bh0, c0, 0, 0, 0);
                c1 = __builtin_amdgcn_mfma_f32_16x16x32_f16(al[1], bh1, c1, 0, 0, 0);
                f32x4 d = c0 + c1;

                const float nm  = *(const float*)(lds + NORMOFS + pb * 4096 + col * 4);
                const float sqm = *(const float*)(lds + NORMOFS + pb * 4096 + 2048 + col * 4);
                const float nmi = __builtin_amdgcn_rcpf(nm);
                float pr[4], s2[4], rc[4];
                #pragma unroll
                for (int ri = 0; ri < 4; ++ri) {
                    pr[ri] = nri[ri] * nmi;
                    s2[ri] = sq_r[ri] + sqm;
                    rc[ri] = __builtin_amdgcn_rcpf(nrE[ri] + nm);
                }
                #pragma unroll
                for (int ri = 0; ri < 4; ++ri) {
                    float dot = d[ri];
                    float cs  = dot * pr[ri];
                    float d2  = fmaxf(fmaf(dot, -2.f, s2[ri]), 0.f);
                    float dn  = __builtin_amdgcn_sqrtf(d2);
                    float a   = __expf(fmaf(dn, -rc[ri], cs));
                    att_f[cti][ri] = a;
                    rs[ri] += a;
                }
            }

            if (p == 1) {
                #pragma unroll
                for (int ri = 0; ri < 4; ++ri) {
                    float v = rs[ri];
                    v += __shfl_xor(v, 1);
                    v += __shfl_xor(v, 2);
                    v += __shfl_xor(v, 4);
                    v += __shfl_xor(v, 8);
                    rs[ri] = v;
                }
                if (l15 == 0) {
                    #pragma unroll
                    for (int ri = 0; ri < 4; ++ri)
                        *(float*)(lds + RSOFS + ((rt * 4 + cg) * 16 + g * 4 + ri) * 4) = rs[ri];
                }
            }
            __syncthreads();
            buf ^= 1;
        }

        #pragma unroll
        for (int ri = 0; ri < 4; ++ri) {
            const int rl = g * 4 + ri;
            float tot = *(const float*)(lds + RSOFS + ((rt * 4 + 0) * 16 + rl) * 4)
                      + *(const float*)(lds + RSOFS + ((rt * 4 + 1) * 16 + rl) * 4)
                      + *(const float*)(lds + RSOFS + ((rt * 4 + 2) * 16 + rl) * 4)
                      + *(const float*)(lds + RSOFS + ((rt * 4 + 3) * 16 + rl) * 4);
            float rinv = __builtin_amdgcn_rcpf(tot + EPS);
            #pragma unroll
            for (int ct = 0; ct < 8; ++ct)
                acc[ct][ri] += att_f[ct][ri] * rinv;
        }
    }

    __syncthreads();
    for (int r = 0; r < 2; ++r) {
        if (rt == r) {
            #pragma unroll
            for (int ri = 0; ri < 4; ++ri)
                #pragma unroll
                for (int ct = 0; ct < 8; ++ct) {
                    const int col = (hs ^ (ct >> 2)) * 256 + cg * 64 + (ct & 3) * 16 + l15;
                    *(float*)(lds + ((g * 4 + ri) * 516 + col) * 4) = acc[ct][ri] * 0.125f;
                }
        }
        __syncthreads();
        #pragma unroll
        for (int it = 0; it < 4; ++it) {
            const int idx4 = tid + it * 512;
            const int row  = idx4 >> 7;
            const int cc   = (idx4 & 127) * 4;
            float4 v = *(const float4*)(lds + (row * 516 + cc) * 4);
            *(float4*)(out + ((size_t)t * NN + n0 + r * 16 + row) * NN + cc) = v;
        }
        __syncthreads();
    }
}

extern "C" void kernel_launch(void* const* d_in, const int* in_sizes, int n_in,
                              void* d_out, int out_size, void* d_ws, size_t ws_size,
                              hipStream_t stream) {
    const float* x    = (const float*)d_in[0];
    const float* W    = (const float*)d_in[1];
    const float* bias = (const float*)d_in[2];
    float* out = (float*)d_out;

    const size_t ZELEMS = (size_t)BB * TT * NN * DD;
    const size_t NROWS  = (size_t)BB * TT * NN;
    _Float16* zh = (_Float16*)d_ws;
    _Float16* zl = zh + ZELEMS;
    float* sqv = (float*)(zh + 2 * ZELEMS);
    float* nvv = sqv + NROWS;
    _Float16* whF = (_Float16*)(nvv + NROWS);   // 16KB
    _Float16* wlF = whF + 8192;                 // 16KB

    wsplit_kernel<<<dim3(1), dim3(256), 0, stream>>>(W, whF, wlF);
    z8_kernel<<<dim3(BB * (NN / 4)), dim3(256), 67584, stream>>>(x, whF, wlF, bias, zh, zl, sqv, nvv);
    att11_kernel<<<dim3(TT * (NN / 32)), dim3(512), LDSSZ_ATT, stream>>>(zh, zl, sqv, nvv, out);
}

// Round 16
// 106.686 us; speedup vs baseline: 1.6141x; 1.0122x over previous
//
#include <hip/hip_runtime.h>
#include <math.h>

#define BB 8
#define NN 512
#define FF 128
#define TT 32
#define DD 64
constexpr float EPS = 1e-6f;

typedef _Float16 half8 __attribute__((ext_vector_type(8)));
typedef float f32x4 __attribute__((ext_vector_type(4)));

extern __shared__ char dynsmem[];

__device__ __forceinline__ float fast_tanh(float v) {
    float e = __expf(2.f * v);
    return 1.f - 2.f * __builtin_amdgcn_rcpf(e + 1.f);
}

// ---------------- Stage 0: split W into MFMA-fragment-layout fp16 hi/lo tables ----------------
__global__ __launch_bounds__(256) void wsplit_kernel(const float* __restrict__ W,
                                                     _Float16* __restrict__ whF,
                                                     _Float16* __restrict__ wlF) {
    const int tid = threadIdx.x;
    #pragma unroll
    for (int k = 0; k < 4; ++k) {
        int u   = tid + k * 256;          // 0..1023
        int g   = u & 3;
        int l15 = (u >> 2) & 15;
        int sd  = u >> 6;                 // s*4+dt
        int s   = sd >> 2;
        int dt  = sd & 3;
        const float* src = W + (dt * 16 + l15) * 128 + s * 32 + g * 8;
        half8 hv, lv;
        #pragma unroll
        for (int i = 0; i < 8; ++i) {
            float f = src[i];
            hv[i] = (_Float16)f;
            lv[i] = (_Float16)(f - (float)hv[i]);
        }
        ((half8*)whF)[u] = hv;
        ((half8*)wlF)[u] = lv;
    }
}

// ---------------- Stage 1: z = tanh(x @ W^T + b) via split-fp16 MFMA (unchanged) ----------------
__global__ __launch_bounds__(256) void z8_kernel(const float* __restrict__ x,
                                                 const _Float16* __restrict__ whF,
                                                 const _Float16* __restrict__ wlF,
                                                 const float* __restrict__ bias,
                                                 _Float16* __restrict__ zh,
                                                 _Float16* __restrict__ zl,
                                                 float* __restrict__ sqv,
                                                 float* __restrict__ nvv) {
    float* xs = (float*)dynsmem;          // 4 waves x 32 t x 132 f (padded)
    const int tid = threadIdx.x;
    const int b  = blockIdx.x >> 7;
    const int n0 = (blockIdx.x & 127) * 4;

    const float4* x4 = (const float4*)(x + ((size_t)b * NN + n0) * FF * TT);
    #pragma unroll
    for (int it = 0; it < 16; ++it) {
        int idx4 = tid + it * 256;
        float4 v = x4[idx4];
        int e   = idx4 * 4;
        int ns  = e >> 12;
        int rem = e & 4095;
        int f   = rem >> 5;
        int t   = rem & 31;
        float* base = xs + ns * 4224 + t * 132 + f;
        base[0 * 132] = v.x;
        base[1 * 132] = v.y;
        base[2 * 132] = v.z;
        base[3 * 132] = v.w;
    }
    __syncthreads();

    const int w    = tid >> 6;
    const int lane = tid & 63;
    const int l15  = lane & 15;
    const int g    = lane >> 4;
    const int n    = n0 + w;
    float* xs_w = xs + w * 4224;

    half8 wh[16];
    #pragma unroll
    for (int sd = 0; sd < 16; ++sd)
        wh[sd] = ((const half8*)whF)[sd * 64 + l15 * 4 + g];

    float bb[4];
    #pragma unroll
    for (int dt = 0; dt < 4; ++dt) bb[dt] = bias[dt * 16 + l15];

    f32x4 acc[4][2];
    #pragma unroll
    for (int dt = 0; dt < 4; ++dt)
        #pragma unroll
        for (int tt = 0; tt < 2; ++tt) acc[dt][tt] = f32x4{0.f, 0.f, 0.f, 0.f};

    #pragma unroll
    for (int s = 0; s < 4; ++s) {
        half8 ah[2], al[2];
        #pragma unroll
        for (int tt = 0; tt < 2; ++tt) {
            const float* ap = xs_w + (tt * 16 + l15) * 132 + s * 32 + g * 8;
            float4 p0 = *(const float4*)ap;
            float4 p1 = *(const float4*)(ap + 4);
            float fv[8] = {p0.x, p0.y, p0.z, p0.w, p1.x, p1.y, p1.z, p1.w};
            #pragma unroll
            for (int i = 0; i < 8; ++i) {
                ah[tt][i] = (_Float16)fv[i];
                al[tt][i] = (_Float16)(fv[i] - (float)ah[tt][i]);
            }
        }
        #pragma unroll
        for (int dt = 0; dt < 4; ++dt) {
            half8 wl_ = ((const half8*)wlF)[(s * 4 + dt) * 64 + l15 * 4 + g];
            acc[dt][0] = __builtin_amdgcn_mfma_f32_16x16x32_f16(ah[0], wh[s * 4 + dt], acc[dt][0], 0, 0, 0);
            acc[dt][1] = __builtin_amdgcn_mfma_f32_16x16x32_f16(ah[1], wh[s * 4 + dt], acc[dt][1], 0, 0, 0);
            acc[dt][0] = __builtin_amdgcn_mfma_f32_16x16x32_f16(al[0], wh[s * 4 + dt], acc[dt][0], 0, 0, 0);
            acc[dt][1] = __builtin_amdgcn_mfma_f32_16x16x32_f16(al[1], wh[s * 4 + dt], acc[dt][1], 0, 0, 0);
            acc[dt][0] = __builtin_amdgcn_mfma_f32_16x16x32_f16(ah[0], wl_, acc[dt][0], 0, 0, 0);
            acc[dt][1] = __builtin_amdgcn_mfma_f32_16x16x32_f16(ah[1], wl_, acc[dt][1], 0, 0, 0);
        }
    }

    float* zsw = xs_w;
    #pragma unroll
    for (int dt = 0; dt < 4; ++dt)
        #pragma unroll
        for (int tt = 0; tt < 2; ++tt)
            #pragma unroll
            for (int ri = 0; ri < 4; ++ri) {
                float zf = fast_tanh(acc[dt][tt][ri] + bb[dt]);
                zsw[(tt * 16 + g * 4 + ri) * 68 + dt * 16 + l15] = zf;
            }

    const int tr = lane >> 1;
    const int ob = (lane & 1) * 4;
    const size_t rowidx = ((size_t)b * TT + tr) * NN + n;
    _Float16* zhp = zh + rowidx * DD;
    _Float16* zlp = zl + rowidx * DD;
    float sqp = 0.f;
    #pragma unroll
    for (int j = 0; j < 4; ++j) {
        int oct = ob + j;
        const float* qp = zsw + tr * 68 + oct * 8;
        float4 q0 = *(const float4*)qp;
        float4 q1 = *(const float4*)(qp + 4);
        float fv[8] = {q0.x, q0.y, q0.z, q0.w, q1.x, q1.y, q1.z, q1.w};
        half8 hv, lv;
        #pragma unroll
        for (int i = 0; i < 8; ++i) {
            sqp += fv[i] * fv[i];
            hv[i] = (_Float16)fv[i];
            lv[i] = (_Float16)(fv[i] - (float)hv[i]);
        }
        const int so = (oct ^ (n & 7)) * 8;
        *(half8*)(zhp + so) = hv;
        *(half8*)(zlp + so) = lv;
    }
    float sqf = sqp + __shfl_xor(sqp, 1);
    if (!(lane & 1)) {
        sqv[rowidx] = sqf;
        nvv[rowidx] = sqrtf(sqf) + EPS;
    }
}

// ---------------- Stage 2: NO LDS staging — B-fragments stream from L2 (working set ~2MB/XCD) ----------------
// grid: 512 blocks (t = bid&31, rowgroup32 = bid>>5), 512 threads = 8 waves.
// wave w: rowtile rt=w>>2 (16 rows), colgroup cg=w&3 (128 cols, 8 ct).
// 1 barrier per b (rs exchange, p-double-buffered). LDS: os[16][516] | rs[2][2][4][16]
#define RSOFS   33024
#define LDSSZ_ATT 34048

__global__ __launch_bounds__(512, 2) void att12_kernel(const _Float16* __restrict__ zh,
                                                       const _Float16* __restrict__ zl,
                                                       const float* __restrict__ sqv,
                                                       const float* __restrict__ nvv,
                                                       float* __restrict__ out) {
    char* lds = dynsmem;
    float* os   = (float*)lds;
    float* rs_s = (float*)(lds + RSOFS);   // [2][2][4][16]
    const int tid  = threadIdx.x;
    const int w    = tid >> 6;
    const int lane = tid & 63;
    const int l15  = lane & 15;
    const int g    = lane >> 4;
    const int rt   = w >> 2;
    const int cg   = w & 3;
    const int t    = blockIdx.x & 31;
    const int rg   = blockIdx.x >> 5;
    const int n0   = rg * 32;

    float acc[8][4];
    #pragma unroll
    for (int ct = 0; ct < 8; ++ct)
        #pragma unroll
        for (int ri = 0; ri < 4; ++ri) acc[ct][ri] = 0.f;

    float att_f[8][4];

    const int arow = n0 + rt * 16 + l15;
    const int ak   = arow & 7;
    const int o0   = (g ^ ak) * 8;           // A octet offsets (elements)
    const int o1   = ((4 + g) ^ ak) * 8;

    for (int b = 0; b < BB; ++b) {
        const int pb = b & 1;
        const size_t nbase = ((size_t)b * TT + t) * NN;
        const size_t slab  = nbase * DD;

        // A fragments from global (swizzled layout)
        half8 ah[2], al[2];
        {
            const size_t ro = slab + (size_t)arow * DD;
            ah[0] = *(const half8*)(zh + ro + o0);
            ah[1] = *(const half8*)(zh + ro + o1);
            al[0] = *(const half8*)(zl + ro + o0);
            al[1] = *(const half8*)(zl + ro + o1);
        }
        // row norms from global (L2-hot)
        float nrE[4], sq_r[4], nri[4];
        #pragma unroll
        for (int ri = 0; ri < 4; ++ri) {
            const int rrow = n0 + rt * 16 + g * 4 + ri;
            float nr = nvv[nbase + rrow];
            sq_r[ri] = sqv[nbase + rrow];
            nri[ri]  = __builtin_amdgcn_rcpf(nr);
            nrE[ri]  = nr + EPS;
        }

        float rs[4] = {0.f, 0.f, 0.f, 0.f};

        // depth-1 prefetch over 8 col-tiles; B zh-frags + col norms straight from L2
        const int col0 = cg * 128 + l15;
        half8 bh0c, bh1c;
        float nmc, sqmc;
        {
            const int kk = col0 & 7;
            const size_t co = slab + (size_t)col0 * DD;
            bh0c = *(const half8*)(zh + co + ((g ^ kk) * 8));
            bh1c = *(const half8*)(zh + co + (((4 + g) ^ kk) * 8));
            nmc  = nvv[nbase + col0];
            sqmc = sqv[nbase + col0];
        }
        #pragma unroll
        for (int ct = 0; ct < 8; ++ct) {
            half8 bh0n, bh1n;
            float nmn, sqmn;
            if (ct < 7) {
                const int col = col0 + (ct + 1) * 16;
                const int kk  = col & 7;
                const size_t co = slab + (size_t)col * DD;
                bh0n = *(const half8*)(zh + co + ((g ^ kk) * 8));
                bh1n = *(const half8*)(zh + co + (((4 + g) ^ kk) * 8));
                nmn  = nvv[nbase + col];
                sqmn = sqv[nbase + col];
            }

            f32x4 c0 = {0.f, 0.f, 0.f, 0.f};
            f32x4 c1 = {0.f, 0.f, 0.f, 0.f};
            c0 = __builtin_amdgcn_mfma_f32_16x16x32_f16(ah[0], bh0c, c0, 0, 0, 0);
            c1 = __builtin_amdgcn_mfma_f32_16x16x32_f16(ah[1], bh1c, c1, 0, 0, 0);
            c0 = __builtin_amdgcn_mfma_f32_16x16x32_f16(al[0], bh0c, c0, 0, 0, 0);
            c1 = __builtin_amdgcn_mfma_f32_16x16x32_f16(al[1], bh1c, c1, 0, 0, 0);
            f32x4 d = c0 + c1;

            const float nmi = __builtin_amdgcn_rcpf(nmc);
            float pr[4], s2[4], rc[4];
            #pragma unroll
            for (int ri = 0; ri < 4; ++ri) {
                pr[ri] = nri[ri] * nmi;
                s2[ri] = sq_r[ri] + sqmc;
                rc[ri] = __builtin_amdgcn_rcpf(nrE[ri] + nmc);
            }
            #pragma unroll
            for (int ri = 0; ri < 4; ++ri) {
                float dot = d[ri];
                float cs  = dot * pr[ri];
                float d2  = fmaxf(fmaf(dot, -2.f, s2[ri]), 0.f);
                float dn  = __builtin_amdgcn_sqrtf(d2);
                float a   = __expf(fmaf(dn, -rc[ri], cs));
                att_f[ct][ri] = a;
                rs[ri] += a;
            }
            bh0c = bh0n; bh1c = bh1n; nmc = nmn; sqmc = sqmn;
        }

        // rs: shfl over 16-lane group, exchange across the 4 cg waves (1 barrier)
        #pragma unroll
        for (int ri = 0; ri < 4; ++ri) {
            float v = rs[ri];
            v += __shfl_xor(v, 1);
            v += __shfl_xor(v, 2);
            v += __shfl_xor(v, 4);
            v += __shfl_xor(v, 8);
            rs[ri] = v;
        }
        if (l15 == 0) {
            #pragma unroll
            for (int ri = 0; ri < 4; ++ri)
                rs_s[((pb * 2 + rt) * 4 + cg) * 16 + g * 4 + ri] = rs[ri];
        }
        __syncthreads();
        #pragma unroll
        for (int ri = 0; ri < 4; ++ri) {
            const int rl = g * 4 + ri;
            const int base = (pb * 2 + rt) * 4;
            float tot = rs_s[(base + 0) * 16 + rl] + rs_s[(base + 1) * 16 + rl]
                      + rs_s[(base + 2) * 16 + rl] + rs_s[(base + 3) * 16 + rl];
            float rinv = __builtin_amdgcn_rcpf(tot + EPS);
            #pragma unroll
            for (int ct = 0; ct < 8; ++ct)
                acc[ct][ri] += att_f[ct][ri] * rinv;
        }
    }

    // out epilogue: two 16-row LDS-transpose rounds
    __syncthreads();
    for (int r = 0; r < 2; ++r) {
        if (rt == r) {
            #pragma unroll
            for (int ri = 0; ri < 4; ++ri)
                #pragma unroll
                for (int ct = 0; ct < 8; ++ct)
                    os[(g * 4 + ri) * 516 + cg * 128 + ct * 16 + l15] = acc[ct][ri] * 0.125f;
        }
        __syncthreads();
        #pragma unroll
        for (int it = 0; it < 4; ++it) {
            const int idx4 = tid + it * 512;
            const int row  = idx4 >> 7;
            const int cc   = (idx4 & 127) * 4;
            float4 v = *(const float4*)&os[row * 516 + cc];
            *(float4*)(out + ((size_t)t * NN + n0 + r * 16 + row) * NN + cc) = v;
        }
        __syncthreads();
    }
}

extern "C" void kernel_launch(void* const* d_in, const int* in_sizes, int n_in,
                              void* d_out, int out_size, void* d_ws, size_t ws_size,
                              hipStream_t stream) {
    const float* x    = (const float*)d_in[0];
    const float* W    = (const float*)d_in[1];
    const float* bias = (const float*)d_in[2];
    float* out = (float*)d_out;

    const size_t ZELEMS = (size_t)BB * TT * NN * DD;
    const size_t NROWS  = (size_t)BB * TT * NN;
    _Float16* zh = (_Float16*)d_ws;
    _Float16* zl = zh + ZELEMS;
    float* sqv = (float*)(zh + 2 * ZELEMS);
    float* nvv = sqv + NROWS;
    _Float16* whF = (_Float16*)(nvv + NROWS);   // 16KB
    _Float16* wlF = whF + 8192;                 // 16KB

    wsplit_kernel<<<dim3(1), dim3(256), 0, stream>>>(W, whF, wlF);
    z8_kernel<<<dim3(BB * (NN / 4)), dim3(256), 67584, stream>>>(x, whF, wlF, bias, zh, zl, sqv, nvv);
    att12_kernel<<<dim3(TT * (NN / 32)), dim3(512), LDSSZ_ATT, stream>>>(zh, zl, sqv, nvv, out);
}